// Round 8
// baseline (956.779 us; speedup 1.0000x reference)
//
#include <hip/hip_runtime.h>

// ---------------------------------------------------------------------------
// SemmaRelModel: two 6-layer NBFNet branches + MLP fusion.
// Round 8:
//  - struct+text phases merged into single launches (block-interleaved) so
//    the latency-bound text branch overlaps the BW-bound struct branch.
//  - 2-row register blocking in update/fuse: one LDS W-fetch feeds 2 rows
//    (LDS:FMA 1:4 -> 1:8; round-7 fuse was LDS-issue-bound at VALU 43%).
//  - CSR build kernels combined (hist/scan/fill for both graphs per launch).
// ---------------------------------------------------------------------------

#define FMA4R(v, wbase, R0, R1, R2, R3) do {                                  \
    const float4* _w = (const float4*)(wbase); float4 _t;                     \
    _t=_w[0]; R0.x=fmaf(v,_t.x,R0.x); R0.y=fmaf(v,_t.y,R0.y); R0.z=fmaf(v,_t.z,R0.z); R0.w=fmaf(v,_t.w,R0.w); \
    _t=_w[1]; R1.x=fmaf(v,_t.x,R1.x); R1.y=fmaf(v,_t.y,R1.y); R1.z=fmaf(v,_t.z,R1.z); R1.w=fmaf(v,_t.w,R1.w); \
    _t=_w[2]; R2.x=fmaf(v,_t.x,R2.x); R2.y=fmaf(v,_t.y,R2.y); R2.z=fmaf(v,_t.z,R2.z); R2.w=fmaf(v,_t.w,R2.w); \
    _t=_w[3]; R3.x=fmaf(v,_t.x,R3.x); R3.y=fmaf(v,_t.y,R3.y); R3.z=fmaf(v,_t.z,R3.z); R3.w=fmaf(v,_t.w,R3.w); \
} while (0)

// one W fetch -> two rows (P* row0, Q* row1)
#define FMA4R2(v0, v1, wbase, P0,P1,P2,P3, Q0,Q1,Q2,Q3) do {                  \
    const float4* _w = (const float4*)(wbase); float4 _t;                     \
    _t=_w[0];                                                                 \
    P0.x=fmaf(v0,_t.x,P0.x); P0.y=fmaf(v0,_t.y,P0.y); P0.z=fmaf(v0,_t.z,P0.z); P0.w=fmaf(v0,_t.w,P0.w); \
    Q0.x=fmaf(v1,_t.x,Q0.x); Q0.y=fmaf(v1,_t.y,Q0.y); Q0.z=fmaf(v1,_t.z,Q0.z); Q0.w=fmaf(v1,_t.w,Q0.w); \
    _t=_w[1];                                                                 \
    P1.x=fmaf(v0,_t.x,P1.x); P1.y=fmaf(v0,_t.y,P1.y); P1.z=fmaf(v0,_t.z,P1.z); P1.w=fmaf(v0,_t.w,P1.w); \
    Q1.x=fmaf(v1,_t.x,Q1.x); Q1.y=fmaf(v1,_t.y,Q1.y); Q1.z=fmaf(v1,_t.z,Q1.z); Q1.w=fmaf(v1,_t.w,Q1.w); \
    _t=_w[2];                                                                 \
    P2.x=fmaf(v0,_t.x,P2.x); P2.y=fmaf(v0,_t.y,P2.y); P2.z=fmaf(v0,_t.z,P2.z); P2.w=fmaf(v0,_t.w,P2.w); \
    Q2.x=fmaf(v1,_t.x,Q2.x); Q2.y=fmaf(v1,_t.y,Q2.y); Q2.z=fmaf(v1,_t.z,Q2.z); Q2.w=fmaf(v1,_t.w,Q2.w); \
    _t=_w[3];                                                                 \
    P3.x=fmaf(v0,_t.x,P3.x); P3.y=fmaf(v0,_t.y,P3.y); P3.z=fmaf(v0,_t.z,P3.z); P3.w=fmaf(v0,_t.w,P3.w); \
    Q3.x=fmaf(v1,_t.x,Q3.x); Q3.y=fmaf(v1,_t.y,Q3.y); Q3.z=fmaf(v1,_t.z,Q3.z); Q3.w=fmaf(v1,_t.w,Q3.w); \
} while (0)

#define SUM4(Ai) ((Ai.x + Ai.y) + (Ai.z + Ai.w))
#define VAR4M(Ai, mm, vv) do { float _c;                                      \
    _c = Ai.x - mm; vv = fmaf(_c, _c, vv); _c = Ai.y - mm; vv = fmaf(_c, _c, vv); \
    _c = Ai.z - mm; vv = fmaf(_c, _c, vv); _c = Ai.w - mm; vv = fmaf(_c, _c, vv); \
} while (0)

#define RSEL(ty) (((ty) < 2) ? ((ty) == 0 ? r0 : r1) : ((ty) == 2 ? r2 : r3))

__global__ __launch_bounds__(256) void k_init_onehot(
    float* __restrict__ x, const int* __restrict__ h_index, int N, int total)
{
    int idx = blockIdx.x * 256 + threadIdx.x;
    if (idx >= total) return;
    int row = idx >> 6;
    int b = row / N;
    int n = row - b * N;
    x[idx] = (n == h_index[b]) ? 1.0f : 0.0f;
}

// ---- CSR build (both graphs per launch) ----
__global__ __launch_bounds__(256) void k_hist_all(
    const int* __restrict__ dst_s, const int* __restrict__ dst_t,
    int* __restrict__ cnt_s, int* __restrict__ cnt_t, int E, int ET)
{
    int i = blockIdx.x * 256 + threadIdx.x;
    if (i < E) atomicAdd(&cnt_s[dst_s[i]], 1);
    else if (i < E + ET) atomicAdd(&cnt_t[dst_t[i - E]], 1);
}

__global__ __launch_bounds__(1024) void k_scan_blk2(
    const int* __restrict__ cnt_s, int* __restrict__ off_s, int* __restrict__ bsum_s,
    const int* __restrict__ cnt_t, int* __restrict__ off_t, int* __restrict__ bsum_t,
    int n, int nb)
{
    bool tpath = blockIdx.x >= nb;
    int lb = tpath ? blockIdx.x - nb : blockIdx.x;
    const int* cnt = tpath ? cnt_t : cnt_s;
    int* off = tpath ? off_t : off_s;
    int* bsum = tpath ? bsum_t : bsum_s;

    __shared__ int wsum[16], wpre[16], tot;
    int tid = threadIdx.x, lane = tid & 63, w = tid >> 6;
    int i = lb * 1024 + tid;
    int v = (i < n) ? cnt[i] : 0;
    int s = v;
    #pragma unroll
    for (int d = 1; d < 64; d <<= 1) {
        int t = __shfl_up(s, d);
        if (lane >= d) s += t;
    }
    if (lane == 63) wsum[w] = s;
    __syncthreads();
    if (w == 0 && lane < 16) {
        int ws = wsum[lane];
        int p = ws;
        #pragma unroll
        for (int d = 1; d < 16; d <<= 1) {
            int t = __shfl_up(p, d);
            if (lane >= d) p += t;
        }
        wpre[lane] = p - ws;
        if (lane == 15) tot = p;
    }
    __syncthreads();
    if (i < n) off[i + 1] = wpre[w] + s;
    if (tid == 0) {
        bsum[lb] = tot;
        if (lb == 0) off[0] = 0;
    }
}

__global__ __launch_bounds__(1024) void k_scan_top2(
    int* __restrict__ bsum_s, int* __restrict__ bsum_t, int nb)
{
    int* bsum = (blockIdx.x == 0) ? bsum_s : bsum_t;
    __shared__ int wsum[16], wpre[16];
    int tid = threadIdx.x, lane = tid & 63, w = tid >> 6;
    int v = (tid < nb) ? bsum[tid] : 0;
    int s = v;
    #pragma unroll
    for (int d = 1; d < 64; d <<= 1) {
        int t = __shfl_up(s, d);
        if (lane >= d) s += t;
    }
    if (lane == 63) wsum[w] = s;
    __syncthreads();
    if (w == 0 && lane < 16) {
        int ws = wsum[lane];
        int p = ws;
        #pragma unroll
        for (int d = 1; d < 16; d <<= 1) {
            int t = __shfl_up(p, d);
            if (lane >= d) p += t;
        }
        wpre[lane] = p - ws;
    }
    __syncthreads();
    if (tid < nb) bsum[tid] = wpre[w] + s - v;
}

__global__ __launch_bounds__(1024) void k_scan_add2(
    const int* __restrict__ bsum_s, int* __restrict__ off_s,
    const int* __restrict__ bsum_t, int* __restrict__ off_t, int n, int nb)
{
    bool tpath = blockIdx.x >= nb;
    int lb = tpath ? blockIdx.x - nb : blockIdx.x;
    int i = lb * 1024 + threadIdx.x;
    if (i < n) (tpath ? off_t : off_s)[i + 1] += (tpath ? bsum_t : bsum_s)[lb];
}

__global__ __launch_bounds__(256) void k_fill_all(
    const int* __restrict__ src_s, const int* __restrict__ dst_s,
    const int* __restrict__ etype,
    const int* __restrict__ off_s, int* __restrict__ cnt_s, int* __restrict__ pk_s,
    const int* __restrict__ src_t, const int* __restrict__ dst_t,
    const int* __restrict__ off_t, int* __restrict__ cnt_t, int* __restrict__ pk_t,
    int E, int ET)
{
    int i = blockIdx.x * 256 + threadIdx.x;
    if (i < E) {
        int d = dst_s[i];
        int pos = off_s[d] + atomicSub(&cnt_s[d], 1) - 1;
        pk_s[pos] = src_s[i] | (etype[i] << 27);
    } else if (i < E + ET) {
        int e = i - E;
        int d = dst_t[e];
        int pos = off_t[d] + atomicSub(&cnt_t[d], 1) - 1;
        pk_t[pos] = src_t[e];
    }
}

// ---- combined aggregation: struct (both batches) + text, interleaved ----
__global__ __launch_bounds__(256) void k_gather_all(
    const float* __restrict__ xs, float* __restrict__ aggs,
    const int* __restrict__ offs, const int* __restrict__ pks,
    const float* __restrict__ rels,      // [4,64]
    const int* __restrict__ hidx,
    const float* __restrict__ xt, float* __restrict__ aggt,
    const int* __restrict__ offt, const int* __restrict__ pkt,
    const float* __restrict__ relt,      // [64]
    const float* __restrict__ init,      // [N,64]
    int N, int sblocks, int tblocks)
{
    int tid = threadIdx.x;
    int lane = tid & 63;
    bool isStruct; int lb;
    if (sblocks == tblocks) { isStruct = !(blockIdx.x & 1); lb = blockIdx.x >> 1; }
    else if ((int)blockIdx.x < sblocks) { isStruct = true; lb = blockIdx.x; }
    else { isStruct = false; lb = blockIdx.x - sblocks; }
    int n = (lb * 256 + tid) >> 6;
    if (n >= N) return;

    if (isStruct) {
        float r0 = rels[lane], r1 = rels[64 + lane];
        float r2 = rels[128 + lane], r3 = rels[192 + lane];
        const float* x0 = xs;
        const float* x1 = xs + (size_t)N * 64;
        float acc0 = (n == hidx[0]) ? 1.0f : 0.0f;
        float acc1 = (n == hidx[1]) ? 1.0f : 0.0f;
        int p0 = __builtin_amdgcn_readfirstlane(offs[n]);
        int p1 = __builtin_amdgcn_readfirstlane(offs[n + 1]);
        for (int p = p0; p < p1; p += 64) {
            int myPk = (p + lane < p1) ? pks[p + lane] : 0;
            int cnt = min(p1 - p, 64);
            int i = 0;
            for (; i + 4 <= cnt; i += 4) {
                int pka = __shfl(myPk, i + 0), pkb = __shfl(myPk, i + 1);
                int pkc = __shfl(myPk, i + 2), pkd = __shfl(myPk, i + 3);
                int sa = pka & 0x03FFFFFF, ta = pka >> 27;
                int sb = pkb & 0x03FFFFFF, tb = pkb >> 27;
                int sc = pkc & 0x03FFFFFF, tc = pkc >> 27;
                int sd = pkd & 0x03FFFFFF, td = pkd >> 27;
                float ra = RSEL(ta), rb = RSEL(tb), rc = RSEL(tc), rd = RSEL(td);
                float a0 = x0[(size_t)sa * 64 + lane], a1 = x1[(size_t)sa * 64 + lane];
                float b0 = x0[(size_t)sb * 64 + lane], b1 = x1[(size_t)sb * 64 + lane];
                float c0 = x0[(size_t)sc * 64 + lane], c1 = x1[(size_t)sc * 64 + lane];
                float d0 = x0[(size_t)sd * 64 + lane], d1 = x1[(size_t)sd * 64 + lane];
                acc0 = fmaf(a0, ra, acc0); acc1 = fmaf(a1, ra, acc1);
                acc0 = fmaf(b0, rb, acc0); acc1 = fmaf(b1, rb, acc1);
                acc0 = fmaf(c0, rc, acc0); acc1 = fmaf(c1, rc, acc1);
                acc0 = fmaf(d0, rd, acc0); acc1 = fmaf(d1, rd, acc1);
            }
            for (; i < cnt; ++i) {
                int pk = __shfl(myPk, i);
                int s = pk & 0x03FFFFFF, ty = pk >> 27;
                float r = RSEL(ty);
                acc0 = fmaf(x0[(size_t)s * 64 + lane], r, acc0);
                acc1 = fmaf(x1[(size_t)s * 64 + lane], r, acc1);
            }
        }
        aggs[(size_t)n * 64 + lane] = acc0;
        aggs[(size_t)(N + n) * 64 + lane] = acc1;
    } else {
        float r = relt[lane];
        float acc = init[(size_t)n * 64 + lane];
        float acc2 = 0.f;
        int p0 = __builtin_amdgcn_readfirstlane(offt[n]);
        int p1 = __builtin_amdgcn_readfirstlane(offt[n + 1]);
        for (int p = p0; p < p1; p += 64) {
            int myPk = (p + lane < p1) ? pkt[p + lane] : 0;
            int cnt = min(p1 - p, 64);
            int i = 0;
            for (; i + 8 <= cnt; i += 8) {
                int s0 = __shfl(myPk, i + 0), s1 = __shfl(myPk, i + 1);
                int s2 = __shfl(myPk, i + 2), s3 = __shfl(myPk, i + 3);
                int s4 = __shfl(myPk, i + 4), s5 = __shfl(myPk, i + 5);
                int s6 = __shfl(myPk, i + 6), s7 = __shfl(myPk, i + 7);
                float a = xt[(size_t)s0 * 64 + lane], b = xt[(size_t)s1 * 64 + lane];
                float c = xt[(size_t)s2 * 64 + lane], d = xt[(size_t)s3 * 64 + lane];
                float e = xt[(size_t)s4 * 64 + lane], f = xt[(size_t)s5 * 64 + lane];
                float g = xt[(size_t)s6 * 64 + lane], h = xt[(size_t)s7 * 64 + lane];
                acc = fmaf(a, r, acc);  acc2 = fmaf(b, r, acc2);
                acc = fmaf(c, r, acc);  acc2 = fmaf(d, r, acc2);
                acc = fmaf(e, r, acc);  acc2 = fmaf(f, r, acc2);
                acc = fmaf(g, r, acc);  acc2 = fmaf(h, r, acc2);
            }
            for (; i < cnt; ++i) {
                int s = __shfl(myPk, i);
                acc = fmaf(xt[(size_t)s * 64 + lane], r, acc);
            }
        }
        aggt[(size_t)n * 64 + lane] = acc + acc2;
    }
}

// generic fallback (B != 2)
__global__ __launch_bounds__(256) void k_gather_struct_gen(
    const float* __restrict__ x, float* __restrict__ agg,
    const int* __restrict__ off, const int* __restrict__ packed,
    const float* __restrict__ rel, const int* __restrict__ h_index,
    int N, int BN)
{
    int wid = (blockIdx.x * 256 + threadIdx.x) >> 6;
    int lane = threadIdx.x & 63;
    if (wid >= BN) return;
    int b = wid / N;
    int n = wid - b * N;
    float r0 = rel[lane], r1 = rel[64 + lane];
    float r2 = rel[128 + lane], r3 = rel[192 + lane];
    const float* xb = x + (size_t)b * N * 64;
    float acc = (n == h_index[b]) ? 1.0f : 0.0f;
    int p0 = off[n], p1 = off[n + 1];
    for (int p = p0; p < p1; ++p) {
        int pk = packed[p];
        int s = pk & 0x03FFFFFF, ty = pk >> 27;
        acc = fmaf(xb[(size_t)s * 64 + lane], RSEL(ty), acc);
    }
    agg[(size_t)wid * 64 + lane] = acc;
}

// ---- combined dense update: 4 threads/row, 2-row register blocking ----
__global__ __launch_bounds__(256) void k_update_all(
    const float* __restrict__ Ws, const float* __restrict__ bs_,
    const float* __restrict__ gs, const float* __restrict__ betas,
    float* __restrict__ xs, const float* __restrict__ aggs, int rows_s,
    const float* __restrict__ Wt, const float* __restrict__ bt_,
    const float* __restrict__ gt_, const float* __restrict__ betat,
    float* __restrict__ xt, const float* __restrict__ aggt, int rows_t,
    int bs_blocks, int bt_blocks)
{
    bool tpath; int lb;
    if (bs_blocks == 2 * bt_blocks) {
        int m3 = blockIdx.x % 3, d3 = blockIdx.x / 3;
        if (m3 != 2) { tpath = false; lb = d3 * 2 + m3; }
        else { tpath = true; lb = d3; }
    } else if ((int)blockIdx.x < bs_blocks) { tpath = false; lb = blockIdx.x; }
    else { tpath = true; lb = blockIdx.x - bs_blocks; }

    const float* W    = tpath ? Wt : Ws;
    const float* bias = tpath ? bt_ : bs_;
    const float* g    = tpath ? gt_ : gs;
    const float* beta = tpath ? betat : betas;
    float* x          = tpath ? xt : xs;
    const float* agg  = tpath ? aggt : aggs;
    int rows          = tpath ? rows_t : rows_s;

    __shared__ float Wl[128 * 64];
    __shared__ float bl[64], gl[64], bel[64];
    int tid = threadIdx.x;
    {
        const float4* W4 = (const float4*)W;
        float4* Wl4 = (float4*)Wl;
        #pragma unroll
        for (int i = 0; i < 8; ++i) Wl4[tid + i * 256] = W4[tid + i * 256];
        if (tid < 64) { bl[tid] = bias[tid]; gl[tid] = g[tid]; bel[tid] = beta[tid]; }
    }
    __syncthreads();

    int gt2 = lb * 256 + tid;
    int pair = gt2 >> 2;
    int q = gt2 & 3, jc = q * 16;
    int r0i = pair * 2, r1i = r0i + 1;
    if (r0i >= rows) return;
    bool h1 = (r1i < rows);
    const float* xr0 = x + (size_t)r0i * 64;
    const float* ar0 = agg + (size_t)r0i * 64;
    const float* xr1 = h1 ? x + (size_t)r1i * 64 : xr0;
    const float* ar1 = h1 ? agg + (size_t)r1i * 64 : ar0;

    const float4* bj = (const float4*)(bl + jc);
    float4 A0 = bj[0], A1 = bj[1], A2 = bj[2], A3 = bj[3];
    float4 B0 = bj[0], B1 = bj[1], B2 = bj[2], B3 = bj[3];

    #pragma unroll
    for (int kb = 0; kb < 64; kb += 4) {
        float4 i0 = *(const float4*)(xr0 + kb);
        float4 i1 = *(const float4*)(xr1 + kb);
        FMA4R2(i0.x, i1.x, Wl + (kb + 0) * 64 + jc, A0,A1,A2,A3, B0,B1,B2,B3);
        FMA4R2(i0.y, i1.y, Wl + (kb + 1) * 64 + jc, A0,A1,A2,A3, B0,B1,B2,B3);
        FMA4R2(i0.z, i1.z, Wl + (kb + 2) * 64 + jc, A0,A1,A2,A3, B0,B1,B2,B3);
        FMA4R2(i0.w, i1.w, Wl + (kb + 3) * 64 + jc, A0,A1,A2,A3, B0,B1,B2,B3);
    }
    #pragma unroll
    for (int kb = 0; kb < 64; kb += 4) {
        float4 i0 = *(const float4*)(ar0 + kb);
        float4 i1 = *(const float4*)(ar1 + kb);
        FMA4R2(i0.x, i1.x, Wl + (64 + kb + 0) * 64 + jc, A0,A1,A2,A3, B0,B1,B2,B3);
        FMA4R2(i0.y, i1.y, Wl + (64 + kb + 1) * 64 + jc, A0,A1,A2,A3, B0,B1,B2,B3);
        FMA4R2(i0.z, i1.z, Wl + (64 + kb + 2) * 64 + jc, A0,A1,A2,A3, B0,B1,B2,B3);
        FMA4R2(i0.w, i1.w, Wl + (64 + kb + 3) * 64 + jc, A0,A1,A2,A3, B0,B1,B2,B3);
    }

    float ls0 = SUM4(A0) + SUM4(A1) + SUM4(A2) + SUM4(A3);
    float ls1 = SUM4(B0) + SUM4(B1) + SUM4(B2) + SUM4(B3);
    ls0 += __shfl_xor(ls0, 1); ls0 += __shfl_xor(ls0, 2);
    ls1 += __shfl_xor(ls1, 1); ls1 += __shfl_xor(ls1, 2);
    float m0 = ls0 * (1.0f / 64.0f), m1 = ls1 * (1.0f / 64.0f);
    float v0 = 0.f, v1 = 0.f;
    VAR4M(A0, m0, v0); VAR4M(A1, m0, v0); VAR4M(A2, m0, v0); VAR4M(A3, m0, v0);
    VAR4M(B0, m1, v1); VAR4M(B1, m1, v1); VAR4M(B2, m1, v1); VAR4M(B3, m1, v1);
    v0 += __shfl_xor(v0, 1); v0 += __shfl_xor(v0, 2);
    v1 += __shfl_xor(v1, 1); v1 += __shfl_xor(v1, 2);
    float inv0 = rsqrtf(v0 * (1.0f / 64.0f) + 1e-5f);
    float inv1 = rsqrtf(v1 * (1.0f / 64.0f) + 1e-5f);

    const float4* gg4 = (const float4*)(gl + jc);
    const float4* bb4 = (const float4*)(bel + jc);
    #define OUTC(Aj, c, mm, iv, xrp, xwp) do {                                \
        float4 xv = ((const float4*)(xrp))[c];                                \
        float4 gg = gg4[c]; float4 bb = bb4[c];                               \
        float4 y;                                                             \
        y.x = fmaxf((Aj.x - mm) * iv * gg.x + bb.x, 0.f) + xv.x;              \
        y.y = fmaxf((Aj.y - mm) * iv * gg.y + bb.y, 0.f) + xv.y;              \
        y.z = fmaxf((Aj.z - mm) * iv * gg.z + bb.z, 0.f) + xv.z;              \
        y.w = fmaxf((Aj.w - mm) * iv * gg.w + bb.w, 0.f) + xv.w;              \
        ((float4*)(xwp))[c] = y; } while (0)
    float* xw0 = x + (size_t)r0i * 64 + jc;
    OUTC(A0, 0, m0, inv0, xr0 + jc, xw0); OUTC(A1, 1, m0, inv0, xr0 + jc, xw0);
    OUTC(A2, 2, m0, inv0, xr0 + jc, xw0); OUTC(A3, 3, m0, inv0, xr0 + jc, xw0);
    if (h1) {
        float* xw1 = x + (size_t)r1i * 64 + jc;
        OUTC(B0, 0, m1, inv1, xr1 + jc, xw1); OUTC(B1, 1, m1, inv1, xr1 + jc, xw1);
        OUTC(B2, 2, m1, inv1, xr1 + jc, xw1); OUTC(B3, 3, m1, inv1, xr1 + jc, xw1);
    }
    #undef OUTC
}

// ---- fusion: 4 threads/row, 2-row blocking, shfl-rotation 2nd GEMV ----
__global__ __launch_bounds__(256) void k_fuse(
    const float* __restrict__ W1, const float* __restrict__ b1,
    const float* __restrict__ W2, const float* __restrict__ b2,
    float* __restrict__ out, const float* __restrict__ z, int N, int rows)
{
    __shared__ float W1l[128 * 64];
    __shared__ float W2l[64 * 64];
    __shared__ float b1l[64], b2l[64];
    int tid = threadIdx.x;
    {
        const float4* Wa = (const float4*)W1;
        float4* Wla = (float4*)W1l;
        #pragma unroll
        for (int i = 0; i < 8; ++i) Wla[tid + i * 256] = Wa[tid + i * 256];
        const float4* Wb = (const float4*)W2;
        float4* Wlb = (float4*)W2l;
        #pragma unroll
        for (int i = 0; i < 4; ++i) Wlb[tid + i * 256] = Wb[tid + i * 256];
        if (tid < 64) { b1l[tid] = b1[tid]; b2l[tid] = b2[tid]; }
    }
    __syncthreads();

    int gt2 = blockIdx.x * 256 + tid;
    int pair = gt2 >> 2;
    int q = gt2 & 3, jc = q * 16;
    int r0i = pair * 2, r1i = r0i + 1;
    if (r0i >= rows) return;
    bool h1 = (r1i < rows);
    int lane = tid & 63;
    int n0 = r0i % N, n1 = r1i % N;
    const float* hr0 = out + (size_t)r0i * 64;
    const float* zr0 = z + (size_t)n0 * 64;
    const float* hr1 = h1 ? out + (size_t)r1i * 64 : hr0;
    const float* zr1 = h1 ? z + (size_t)n1 * 64 : zr0;

    const float4* bj = (const float4*)(b1l + jc);
    float4 FA0 = bj[0], FA1 = bj[1], FA2 = bj[2], FA3 = bj[3];
    float4 FB0 = bj[0], FB1 = bj[1], FB2 = bj[2], FB3 = bj[3];
    #pragma unroll
    for (int kb = 0; kb < 64; kb += 4) {
        float4 i0 = *(const float4*)(hr0 + kb);
        float4 i1 = *(const float4*)(hr1 + kb);
        FMA4R2(i0.x, i1.x, W1l + (kb + 0) * 64 + jc, FA0,FA1,FA2,FA3, FB0,FB1,FB2,FB3);
        FMA4R2(i0.y, i1.y, W1l + (kb + 1) * 64 + jc, FA0,FA1,FA2,FA3, FB0,FB1,FB2,FB3);
        FMA4R2(i0.z, i1.z, W1l + (kb + 2) * 64 + jc, FA0,FA1,FA2,FA3, FB0,FB1,FB2,FB3);
        FMA4R2(i0.w, i1.w, W1l + (kb + 3) * 64 + jc, FA0,FA1,FA2,FA3, FB0,FB1,FB2,FB3);
    }
    #pragma unroll
    for (int kb = 0; kb < 64; kb += 4) {
        float4 i0 = *(const float4*)(zr0 + kb);
        float4 i1 = *(const float4*)(zr1 + kb);
        FMA4R2(i0.x, i1.x, W1l + (64 + kb + 0) * 64 + jc, FA0,FA1,FA2,FA3, FB0,FB1,FB2,FB3);
        FMA4R2(i0.y, i1.y, W1l + (64 + kb + 1) * 64 + jc, FA0,FA1,FA2,FA3, FB0,FB1,FB2,FB3);
        FMA4R2(i0.z, i1.z, W1l + (64 + kb + 2) * 64 + jc, FA0,FA1,FA2,FA3, FB0,FB1,FB2,FB3);
        FMA4R2(i0.w, i1.w, W1l + (64 + kb + 3) * 64 + jc, FA0,FA1,FA2,FA3, FB0,FB1,FB2,FB3);
    }
    #define RELU4(Ai) do { Ai.x = fmaxf(Ai.x, 0.f); Ai.y = fmaxf(Ai.y, 0.f); \
                           Ai.z = fmaxf(Ai.z, 0.f); Ai.w = fmaxf(Ai.w, 0.f); } while (0)
    RELU4(FA0); RELU4(FA1); RELU4(FA2); RELU4(FA3);
    RELU4(FB0); RELU4(FB1); RELU4(FB2); RELU4(FB3);
    #undef RELU4

    const float4* bj2 = (const float4*)(b2l + jc);
    float4 OA0 = bj2[0], OA1 = bj2[1], OA2 = bj2[2], OA3 = bj2[3];
    float4 OB0 = bj2[0], OB1 = bj2[1], OB2 = bj2[2], OB3 = bj2[3];
    int srcLane = (lane & ~3) | ((q + 1) & 3);
    #pragma unroll
    for (int s = 0; s < 4; ++s) {
        int c = (q + s) & 3;
        const float* w2 = W2l + (c * 16) * 64 + jc;
        FMA4R2(FA0.x, FB0.x, w2 + 0 * 64,  OA0,OA1,OA2,OA3, OB0,OB1,OB2,OB3);
        FMA4R2(FA0.y, FB0.y, w2 + 1 * 64,  OA0,OA1,OA2,OA3, OB0,OB1,OB2,OB3);
        FMA4R2(FA0.z, FB0.z, w2 + 2 * 64,  OA0,OA1,OA2,OA3, OB0,OB1,OB2,OB3);
        FMA4R2(FA0.w, FB0.w, w2 + 3 * 64,  OA0,OA1,OA2,OA3, OB0,OB1,OB2,OB3);
        FMA4R2(FA1.x, FB1.x, w2 + 4 * 64,  OA0,OA1,OA2,OA3, OB0,OB1,OB2,OB3);
        FMA4R2(FA1.y, FB1.y, w2 + 5 * 64,  OA0,OA1,OA2,OA3, OB0,OB1,OB2,OB3);
        FMA4R2(FA1.z, FB1.z, w2 + 6 * 64,  OA0,OA1,OA2,OA3, OB0,OB1,OB2,OB3);
        FMA4R2(FA1.w, FB1.w, w2 + 7 * 64,  OA0,OA1,OA2,OA3, OB0,OB1,OB2,OB3);
        FMA4R2(FA2.x, FB2.x, w2 + 8 * 64,  OA0,OA1,OA2,OA3, OB0,OB1,OB2,OB3);
        FMA4R2(FA2.y, FB2.y, w2 + 9 * 64,  OA0,OA1,OA2,OA3, OB0,OB1,OB2,OB3);
        FMA4R2(FA2.z, FB2.z, w2 + 10 * 64, OA0,OA1,OA2,OA3, OB0,OB1,OB2,OB3);
        FMA4R2(FA2.w, FB2.w, w2 + 11 * 64, OA0,OA1,OA2,OA3, OB0,OB1,OB2,OB3);
        FMA4R2(FA3.x, FB3.x, w2 + 12 * 64, OA0,OA1,OA2,OA3, OB0,OB1,OB2,OB3);
        FMA4R2(FA3.y, FB3.y, w2 + 13 * 64, OA0,OA1,OA2,OA3, OB0,OB1,OB2,OB3);
        FMA4R2(FA3.z, FB3.z, w2 + 14 * 64, OA0,OA1,OA2,OA3, OB0,OB1,OB2,OB3);
        FMA4R2(FA3.w, FB3.w, w2 + 15 * 64, OA0,OA1,OA2,OA3, OB0,OB1,OB2,OB3);
        if (s < 3) {
            FA0.x = __shfl(FA0.x, srcLane); FA0.y = __shfl(FA0.y, srcLane);
            FA0.z = __shfl(FA0.z, srcLane); FA0.w = __shfl(FA0.w, srcLane);
            FA1.x = __shfl(FA1.x, srcLane); FA1.y = __shfl(FA1.y, srcLane);
            FA1.z = __shfl(FA1.z, srcLane); FA1.w = __shfl(FA1.w, srcLane);
            FA2.x = __shfl(FA2.x, srcLane); FA2.y = __shfl(FA2.y, srcLane);
            FA2.z = __shfl(FA2.z, srcLane); FA2.w = __shfl(FA2.w, srcLane);
            FA3.x = __shfl(FA3.x, srcLane); FA3.y = __shfl(FA3.y, srcLane);
            FA3.z = __shfl(FA3.z, srcLane); FA3.w = __shfl(FA3.w, srcLane);
            FB0.x = __shfl(FB0.x, srcLane); FB0.y = __shfl(FB0.y, srcLane);
            FB0.z = __shfl(FB0.z, srcLane); FB0.w = __shfl(FB0.w, srcLane);
            FB1.x = __shfl(FB1.x, srcLane); FB1.y = __shfl(FB1.y, srcLane);
            FB1.z = __shfl(FB1.z, srcLane); FB1.w = __shfl(FB1.w, srcLane);
            FB2.x = __shfl(FB2.x, srcLane); FB2.y = __shfl(FB2.y, srcLane);
            FB2.z = __shfl(FB2.z, srcLane); FB2.w = __shfl(FB2.w, srcLane);
            FB3.x = __shfl(FB3.x, srcLane); FB3.y = __shfl(FB3.y, srcLane);
            FB3.z = __shfl(FB3.z, srcLane); FB3.w = __shfl(FB3.w, srcLane);
        }
    }
    float4* ow0 = (float4*)(out + (size_t)r0i * 64 + jc);
    ow0[0] = OA0; ow0[1] = OA1; ow0[2] = OA2; ow0[3] = OA3;
    if (h1) {
        float4* ow1 = (float4*)(out + (size_t)r1i * 64 + jc);
        ow1[0] = OB0; ow1[1] = OB1; ow1[2] = OB2; ow1[3] = OB3;
    }
}

extern "C" void kernel_launch(void* const* d_in, const int* in_sizes, int n_in,
                              void* d_out, int out_size, void* d_ws, size_t ws_size,
                              hipStream_t stream)
{
    const float* rel_text_init = (const float*)d_in[0];
    const float* struct_rel    = (const float*)d_in[1];
    const float* struct_W      = (const float*)d_in[2];
    const float* struct_b      = (const float*)d_in[3];
    const float* struct_g      = (const float*)d_in[4];
    const float* struct_beta   = (const float*)d_in[5];
    const float* text_rel      = (const float*)d_in[6];
    const float* text_W        = (const float*)d_in[7];
    const float* text_b        = (const float*)d_in[8];
    const float* text_g        = (const float*)d_in[9];
    const float* text_beta     = (const float*)d_in[10];
    const float* fuse_W1       = (const float*)d_in[11];
    const float* fuse_b1       = (const float*)d_in[12];
    const float* fuse_W2       = (const float*)d_in[13];
    const float* fuse_b2       = (const float*)d_in[14];
    const int*   h_index       = (const int*)d_in[15];
    const int*   edge_index    = (const int*)d_in[16];
    const int*   edge_type     = (const int*)d_in[17];
    const int*   text_edge_idx = (const int*)d_in[18];

    const int B  = in_sizes[15];
    const int N  = in_sizes[0] / 64;
    const int E  = in_sizes[17];
    const int ET = in_sizes[18] / 2;
    const int L  = in_sizes[3] / 64;
    const int R  = in_sizes[1] / (L * 64);

    const int* src  = edge_index;
    const int* dst  = edge_index + E;
    const int* tsrc = text_edge_idx;
    const int* tdst = text_edge_idx + ET;

    // ---- workspace layout ----
    float* x_t   = (float*)d_ws;                     // [N,64]
    float* agg_t = x_t + (size_t)N * 64;             // [N,64]
    float* agg_s = agg_t + (size_t)N * 64;           // [B,N,64]
    int*   cnt_s = (int*)(agg_s + (size_t)B * N * 64);  // [N]
    int*   off_s = cnt_s + N;                        // [N+1]
    int*   pk_s  = off_s + N + 1;                    // [E]
    int*   cnt_t = pk_s + E;                         // [N]
    int*   off_t = cnt_t + N;                        // [N+1]
    int*   pk_t  = off_t + N + 1;                    // [ET]
    int*   bsum_s = pk_t + ET;                       // [<=1024]
    int*   bsum_t = bsum_s + 1024;                   // [<=1024]

    float* x_s = (float*)d_out;                      // [B,N,64]

    const size_t nd  = (size_t)N * 64;
    const int rows_s = B * N;
    const int tot_s  = rows_s * 64;
    const int nb     = (N + 1023) / 1024;

    const int gb_init   = (tot_s + 255) / 256;
    const int gb_hist   = (E + ET + 255) / 256;
    const int gb_wave_n = (N * 64 + 255) / 256;            // per-branch gather blocks
    const int pairs_s   = (rows_s + 1) / 2;
    const int pairs_t   = (N + 1) / 2;
    const int bs_blocks = (pairs_s * 4 + 255) / 256;
    const int bt_blocks = (pairs_t * 4 + 255) / 256;
    const int gb_fuse   = bs_blocks;

    // ---- CSR builds ----
    hipMemsetAsync(cnt_s, 0, (size_t)N * 4, stream);
    hipMemsetAsync(cnt_t, 0, (size_t)N * 4, stream);
    k_hist_all<<<gb_hist, 256, 0, stream>>>(dst, tdst, cnt_s, cnt_t, E, ET);
    k_scan_blk2<<<2 * nb, 1024, 0, stream>>>(cnt_s, off_s, bsum_s,
                                             cnt_t, off_t, bsum_t, N, nb);
    k_scan_top2<<<2, 1024, 0, stream>>>(bsum_s, bsum_t, nb);
    k_scan_add2<<<2 * nb, 1024, 0, stream>>>(bsum_s, off_s, bsum_t, off_t, N, nb);
    k_fill_all<<<gb_hist, 256, 0, stream>>>(src, dst, edge_type, off_s, cnt_s, pk_s,
                                            tsrc, tdst, off_t, cnt_t, pk_t, E, ET);

    // ---- boundaries ----
    k_init_onehot<<<gb_init, 256, 0, stream>>>(x_s, h_index, N, tot_s);
    hipMemcpyAsync(x_t, rel_text_init, nd * sizeof(float),
                   hipMemcpyDeviceToDevice, stream);

    // ---- 6 layers, both branches per launch ----
    for (int i = 0; i < L; ++i) {
        if (B == 2) {
            k_gather_all<<<2 * gb_wave_n, 256, 0, stream>>>(
                x_s, agg_s, off_s, pk_s, struct_rel + (size_t)i * R * 64, h_index,
                x_t, agg_t, off_t, pk_t, text_rel + (size_t)i * 64, rel_text_init,
                N, gb_wave_n, gb_wave_n);
        } else {
            k_gather_struct_gen<<<(rows_s * 64 + 255) / 256, 256, 0, stream>>>(
                x_s, agg_s, off_s, pk_s,
                struct_rel + (size_t)i * R * 64, h_index, N, rows_s);
            k_gather_all<<<gb_wave_n, 256, 0, stream>>>(
                x_s, agg_s, off_s, pk_s, struct_rel + (size_t)i * R * 64, h_index,
                x_t, agg_t, off_t, pk_t, text_rel + (size_t)i * 64, rel_text_init,
                N, 0, gb_wave_n);
        }
        k_update_all<<<bs_blocks + bt_blocks, 256, 0, stream>>>(
            struct_W + (size_t)i * 128 * 64, struct_b + i * 64,
            struct_g + i * 64, struct_beta + i * 64, x_s, agg_s, rows_s,
            text_W + (size_t)i * 128 * 64, text_b + i * 64,
            text_g + i * 64, text_beta + i * 64, x_t, agg_t, N,
            bs_blocks, bt_blocks);
    }

    // ---- fusion ----
    k_fuse<<<gb_fuse, 256, 0, stream>>>(
        fuse_W1, fuse_b1, fuse_W2, fuse_b2, x_s, x_t, N, rows_s);
}

// Round 9
// 720.141 us; speedup vs baseline: 1.3286x; 1.3286x over previous
//
#include <hip/hip_runtime.h>

// ---------------------------------------------------------------------------
// SemmaRelModel: two 6-layer NBFNet branches + MLP fusion.
// Round 9: revert k_fuse to round-7 single-row form (round-8's 2-row fuse
//   spilled: VGPR 256, 842MB scratch traffic, 62->341us). Keep round-8's
//   merged gather/update structure (it saved ~120us on the non-fuse time).
// ---------------------------------------------------------------------------

#define FMA4R(v, wbase, R0, R1, R2, R3) do {                                  \
    const float4* _w = (const float4*)(wbase); float4 _t;                     \
    _t=_w[0]; R0.x=fmaf(v,_t.x,R0.x); R0.y=fmaf(v,_t.y,R0.y); R0.z=fmaf(v,_t.z,R0.z); R0.w=fmaf(v,_t.w,R0.w); \
    _t=_w[1]; R1.x=fmaf(v,_t.x,R1.x); R1.y=fmaf(v,_t.y,R1.y); R1.z=fmaf(v,_t.z,R1.z); R1.w=fmaf(v,_t.w,R1.w); \
    _t=_w[2]; R2.x=fmaf(v,_t.x,R2.x); R2.y=fmaf(v,_t.y,R2.y); R2.z=fmaf(v,_t.z,R2.z); R2.w=fmaf(v,_t.w,R2.w); \
    _t=_w[3]; R3.x=fmaf(v,_t.x,R3.x); R3.y=fmaf(v,_t.y,R3.y); R3.z=fmaf(v,_t.z,R3.z); R3.w=fmaf(v,_t.w,R3.w); \
} while (0)

// one W fetch -> two rows (P* row0, Q* row1)
#define FMA4R2(v0, v1, wbase, P0,P1,P2,P3, Q0,Q1,Q2,Q3) do {                  \
    const float4* _w = (const float4*)(wbase); float4 _t;                     \
    _t=_w[0];                                                                 \
    P0.x=fmaf(v0,_t.x,P0.x); P0.y=fmaf(v0,_t.y,P0.y); P0.z=fmaf(v0,_t.z,P0.z); P0.w=fmaf(v0,_t.w,P0.w); \
    Q0.x=fmaf(v1,_t.x,Q0.x); Q0.y=fmaf(v1,_t.y,Q0.y); Q0.z=fmaf(v1,_t.z,Q0.z); Q0.w=fmaf(v1,_t.w,Q0.w); \
    _t=_w[1];                                                                 \
    P1.x=fmaf(v0,_t.x,P1.x); P1.y=fmaf(v0,_t.y,P1.y); P1.z=fmaf(v0,_t.z,P1.z); P1.w=fmaf(v0,_t.w,P1.w); \
    Q1.x=fmaf(v1,_t.x,Q1.x); Q1.y=fmaf(v1,_t.y,Q1.y); Q1.z=fmaf(v1,_t.z,Q1.z); Q1.w=fmaf(v1,_t.w,Q1.w); \
    _t=_w[2];                                                                 \
    P2.x=fmaf(v0,_t.x,P2.x); P2.y=fmaf(v0,_t.y,P2.y); P2.z=fmaf(v0,_t.z,P2.z); P2.w=fmaf(v0,_t.w,P2.w); \
    Q2.x=fmaf(v1,_t.x,Q2.x); Q2.y=fmaf(v1,_t.y,Q2.y); Q2.z=fmaf(v1,_t.z,Q2.z); Q2.w=fmaf(v1,_t.w,Q2.w); \
    _t=_w[3];                                                                 \
    P3.x=fmaf(v0,_t.x,P3.x); P3.y=fmaf(v0,_t.y,P3.y); P3.z=fmaf(v0,_t.z,P3.z); P3.w=fmaf(v0,_t.w,P3.w); \
    Q3.x=fmaf(v1,_t.x,Q3.x); Q3.y=fmaf(v1,_t.y,Q3.y); Q3.z=fmaf(v1,_t.z,Q3.z); Q3.w=fmaf(v1,_t.w,Q3.w); \
} while (0)

#define SUM4(Ai) ((Ai.x + Ai.y) + (Ai.z + Ai.w))
#define VAR4M(Ai, mm, vv) do { float _c;                                      \
    _c = Ai.x - mm; vv = fmaf(_c, _c, vv); _c = Ai.y - mm; vv = fmaf(_c, _c, vv); \
    _c = Ai.z - mm; vv = fmaf(_c, _c, vv); _c = Ai.w - mm; vv = fmaf(_c, _c, vv); \
} while (0)

#define RSEL(ty) (((ty) < 2) ? ((ty) == 0 ? r0 : r1) : ((ty) == 2 ? r2 : r3))

__global__ __launch_bounds__(256) void k_init_onehot(
    float* __restrict__ x, const int* __restrict__ h_index, int N, int total)
{
    int idx = blockIdx.x * 256 + threadIdx.x;
    if (idx >= total) return;
    int row = idx >> 6;
    int b = row / N;
    int n = row - b * N;
    x[idx] = (n == h_index[b]) ? 1.0f : 0.0f;
}

// ---- CSR build (both graphs per launch) ----
__global__ __launch_bounds__(256) void k_hist_all(
    const int* __restrict__ dst_s, const int* __restrict__ dst_t,
    int* __restrict__ cnt_s, int* __restrict__ cnt_t, int E, int ET)
{
    int i = blockIdx.x * 256 + threadIdx.x;
    if (i < E) atomicAdd(&cnt_s[dst_s[i]], 1);
    else if (i < E + ET) atomicAdd(&cnt_t[dst_t[i - E]], 1);
}

__global__ __launch_bounds__(1024) void k_scan_blk2(
    const int* __restrict__ cnt_s, int* __restrict__ off_s, int* __restrict__ bsum_s,
    const int* __restrict__ cnt_t, int* __restrict__ off_t, int* __restrict__ bsum_t,
    int n, int nb)
{
    bool tpath = blockIdx.x >= nb;
    int lb = tpath ? blockIdx.x - nb : blockIdx.x;
    const int* cnt = tpath ? cnt_t : cnt_s;
    int* off = tpath ? off_t : off_s;
    int* bsum = tpath ? bsum_t : bsum_s;

    __shared__ int wsum[16], wpre[16], tot;
    int tid = threadIdx.x, lane = tid & 63, w = tid >> 6;
    int i = lb * 1024 + tid;
    int v = (i < n) ? cnt[i] : 0;
    int s = v;
    #pragma unroll
    for (int d = 1; d < 64; d <<= 1) {
        int t = __shfl_up(s, d);
        if (lane >= d) s += t;
    }
    if (lane == 63) wsum[w] = s;
    __syncthreads();
    if (w == 0 && lane < 16) {
        int ws = wsum[lane];
        int p = ws;
        #pragma unroll
        for (int d = 1; d < 16; d <<= 1) {
            int t = __shfl_up(p, d);
            if (lane >= d) p += t;
        }
        wpre[lane] = p - ws;
        if (lane == 15) tot = p;
    }
    __syncthreads();
    if (i < n) off[i + 1] = wpre[w] + s;
    if (tid == 0) {
        bsum[lb] = tot;
        if (lb == 0) off[0] = 0;
    }
}

__global__ __launch_bounds__(1024) void k_scan_top2(
    int* __restrict__ bsum_s, int* __restrict__ bsum_t, int nb)
{
    int* bsum = (blockIdx.x == 0) ? bsum_s : bsum_t;
    __shared__ int wsum[16], wpre[16];
    int tid = threadIdx.x, lane = tid & 63, w = tid >> 6;
    int v = (tid < nb) ? bsum[tid] : 0;
    int s = v;
    #pragma unroll
    for (int d = 1; d < 64; d <<= 1) {
        int t = __shfl_up(s, d);
        if (lane >= d) s += t;
    }
    if (lane == 63) wsum[w] = s;
    __syncthreads();
    if (w == 0 && lane < 16) {
        int ws = wsum[lane];
        int p = ws;
        #pragma unroll
        for (int d = 1; d < 16; d <<= 1) {
            int t = __shfl_up(p, d);
            if (lane >= d) p += t;
        }
        wpre[lane] = p - ws;
    }
    __syncthreads();
    if (tid < nb) bsum[tid] = wpre[w] + s - v;
}

__global__ __launch_bounds__(1024) void k_scan_add2(
    const int* __restrict__ bsum_s, int* __restrict__ off_s,
    const int* __restrict__ bsum_t, int* __restrict__ off_t, int n, int nb)
{
    bool tpath = blockIdx.x >= nb;
    int lb = tpath ? blockIdx.x - nb : blockIdx.x;
    int i = lb * 1024 + threadIdx.x;
    if (i < n) (tpath ? off_t : off_s)[i + 1] += (tpath ? bsum_t : bsum_s)[lb];
}

__global__ __launch_bounds__(256) void k_fill_all(
    const int* __restrict__ src_s, const int* __restrict__ dst_s,
    const int* __restrict__ etype,
    const int* __restrict__ off_s, int* __restrict__ cnt_s, int* __restrict__ pk_s,
    const int* __restrict__ src_t, const int* __restrict__ dst_t,
    const int* __restrict__ off_t, int* __restrict__ cnt_t, int* __restrict__ pk_t,
    int E, int ET)
{
    int i = blockIdx.x * 256 + threadIdx.x;
    if (i < E) {
        int d = dst_s[i];
        int pos = off_s[d] + atomicSub(&cnt_s[d], 1) - 1;
        pk_s[pos] = src_s[i] | (etype[i] << 27);
    } else if (i < E + ET) {
        int e = i - E;
        int d = dst_t[e];
        int pos = off_t[d] + atomicSub(&cnt_t[d], 1) - 1;
        pk_t[pos] = src_t[e];
    }
}

// ---- combined aggregation: struct (both batches) + text, interleaved ----
__global__ __launch_bounds__(256) void k_gather_all(
    const float* __restrict__ xs, float* __restrict__ aggs,
    const int* __restrict__ offs, const int* __restrict__ pks,
    const float* __restrict__ rels,      // [4,64]
    const int* __restrict__ hidx,
    const float* __restrict__ xt, float* __restrict__ aggt,
    const int* __restrict__ offt, const int* __restrict__ pkt,
    const float* __restrict__ relt,      // [64]
    const float* __restrict__ init,      // [N,64]
    int N, int sblocks, int tblocks)
{
    int tid = threadIdx.x;
    int lane = tid & 63;
    bool isStruct; int lb;
    if (sblocks == tblocks) { isStruct = !(blockIdx.x & 1); lb = blockIdx.x >> 1; }
    else if ((int)blockIdx.x < sblocks) { isStruct = true; lb = blockIdx.x; }
    else { isStruct = false; lb = blockIdx.x - sblocks; }
    int n = (lb * 256 + tid) >> 6;
    if (n >= N) return;

    if (isStruct) {
        float r0 = rels[lane], r1 = rels[64 + lane];
        float r2 = rels[128 + lane], r3 = rels[192 + lane];
        const float* x0 = xs;
        const float* x1 = xs + (size_t)N * 64;
        float acc0 = (n == hidx[0]) ? 1.0f : 0.0f;
        float acc1 = (n == hidx[1]) ? 1.0f : 0.0f;
        int p0 = __builtin_amdgcn_readfirstlane(offs[n]);
        int p1 = __builtin_amdgcn_readfirstlane(offs[n + 1]);
        for (int p = p0; p < p1; p += 64) {
            int myPk = (p + lane < p1) ? pks[p + lane] : 0;
            int cnt = min(p1 - p, 64);
            int i = 0;
            for (; i + 4 <= cnt; i += 4) {
                int pka = __shfl(myPk, i + 0), pkb = __shfl(myPk, i + 1);
                int pkc = __shfl(myPk, i + 2), pkd = __shfl(myPk, i + 3);
                int sa = pka & 0x03FFFFFF, ta = pka >> 27;
                int sb = pkb & 0x03FFFFFF, tb = pkb >> 27;
                int sc = pkc & 0x03FFFFFF, tc = pkc >> 27;
                int sd = pkd & 0x03FFFFFF, td = pkd >> 27;
                float ra = RSEL(ta), rb = RSEL(tb), rc = RSEL(tc), rd = RSEL(td);
                float a0 = x0[(size_t)sa * 64 + lane], a1 = x1[(size_t)sa * 64 + lane];
                float b0 = x0[(size_t)sb * 64 + lane], b1 = x1[(size_t)sb * 64 + lane];
                float c0 = x0[(size_t)sc * 64 + lane], c1 = x1[(size_t)sc * 64 + lane];
                float d0 = x0[(size_t)sd * 64 + lane], d1 = x1[(size_t)sd * 64 + lane];
                acc0 = fmaf(a0, ra, acc0); acc1 = fmaf(a1, ra, acc1);
                acc0 = fmaf(b0, rb, acc0); acc1 = fmaf(b1, rb, acc1);
                acc0 = fmaf(c0, rc, acc0); acc1 = fmaf(c1, rc, acc1);
                acc0 = fmaf(d0, rd, acc0); acc1 = fmaf(d1, rd, acc1);
            }
            for (; i < cnt; ++i) {
                int pk = __shfl(myPk, i);
                int s = pk & 0x03FFFFFF, ty = pk >> 27;
                float r = RSEL(ty);
                acc0 = fmaf(x0[(size_t)s * 64 + lane], r, acc0);
                acc1 = fmaf(x1[(size_t)s * 64 + lane], r, acc1);
            }
        }
        aggs[(size_t)n * 64 + lane] = acc0;
        aggs[(size_t)(N + n) * 64 + lane] = acc1;
    } else {
        float r = relt[lane];
        float acc = init[(size_t)n * 64 + lane];
        float acc2 = 0.f;
        int p0 = __builtin_amdgcn_readfirstlane(offt[n]);
        int p1 = __builtin_amdgcn_readfirstlane(offt[n + 1]);
        for (int p = p0; p < p1; p += 64) {
            int myPk = (p + lane < p1) ? pkt[p + lane] : 0;
            int cnt = min(p1 - p, 64);
            int i = 0;
            for (; i + 8 <= cnt; i += 8) {
                int s0 = __shfl(myPk, i + 0), s1 = __shfl(myPk, i + 1);
                int s2 = __shfl(myPk, i + 2), s3 = __shfl(myPk, i + 3);
                int s4 = __shfl(myPk, i + 4), s5 = __shfl(myPk, i + 5);
                int s6 = __shfl(myPk, i + 6), s7 = __shfl(myPk, i + 7);
                float a = xt[(size_t)s0 * 64 + lane], b = xt[(size_t)s1 * 64 + lane];
                float c = xt[(size_t)s2 * 64 + lane], d = xt[(size_t)s3 * 64 + lane];
                float e = xt[(size_t)s4 * 64 + lane], f = xt[(size_t)s5 * 64 + lane];
                float g = xt[(size_t)s6 * 64 + lane], h = xt[(size_t)s7 * 64 + lane];
                acc = fmaf(a, r, acc);  acc2 = fmaf(b, r, acc2);
                acc = fmaf(c, r, acc);  acc2 = fmaf(d, r, acc2);
                acc = fmaf(e, r, acc);  acc2 = fmaf(f, r, acc2);
                acc = fmaf(g, r, acc);  acc2 = fmaf(h, r, acc2);
            }
            for (; i < cnt; ++i) {
                int s = __shfl(myPk, i);
                acc = fmaf(xt[(size_t)s * 64 + lane], r, acc);
            }
        }
        aggt[(size_t)n * 64 + lane] = acc + acc2;
    }
}

// generic fallback (B != 2)
__global__ __launch_bounds__(256) void k_gather_struct_gen(
    const float* __restrict__ x, float* __restrict__ agg,
    const int* __restrict__ off, const int* __restrict__ packed,
    const float* __restrict__ rel, const int* __restrict__ h_index,
    int N, int BN)
{
    int wid = (blockIdx.x * 256 + threadIdx.x) >> 6;
    int lane = threadIdx.x & 63;
    if (wid >= BN) return;
    int b = wid / N;
    int n = wid - b * N;
    float r0 = rel[lane], r1 = rel[64 + lane];
    float r2 = rel[128 + lane], r3 = rel[192 + lane];
    const float* xb = x + (size_t)b * N * 64;
    float acc = (n == h_index[b]) ? 1.0f : 0.0f;
    int p0 = off[n], p1 = off[n + 1];
    for (int p = p0; p < p1; ++p) {
        int pk = packed[p];
        int s = pk & 0x03FFFFFF, ty = pk >> 27;
        acc = fmaf(xb[(size_t)s * 64 + lane], RSEL(ty), acc);
    }
    agg[(size_t)wid * 64 + lane] = acc;
}

// ---- combined dense update: 4 threads/row, 2-row register blocking ----
__global__ __launch_bounds__(256) void k_update_all(
    const float* __restrict__ Ws, const float* __restrict__ bs_,
    const float* __restrict__ gs, const float* __restrict__ betas,
    float* __restrict__ xs, const float* __restrict__ aggs, int rows_s,
    const float* __restrict__ Wt, const float* __restrict__ bt_,
    const float* __restrict__ gt_, const float* __restrict__ betat,
    float* __restrict__ xt, const float* __restrict__ aggt, int rows_t,
    int bs_blocks, int bt_blocks)
{
    bool tpath; int lb;
    if (bs_blocks == 2 * bt_blocks) {
        int m3 = blockIdx.x % 3, d3 = blockIdx.x / 3;
        if (m3 != 2) { tpath = false; lb = d3 * 2 + m3; }
        else { tpath = true; lb = d3; }
    } else if ((int)blockIdx.x < bs_blocks) { tpath = false; lb = blockIdx.x; }
    else { tpath = true; lb = blockIdx.x - bs_blocks; }

    const float* W    = tpath ? Wt : Ws;
    const float* bias = tpath ? bt_ : bs_;
    const float* g    = tpath ? gt_ : gs;
    const float* beta = tpath ? betat : betas;
    float* x          = tpath ? xt : xs;
    const float* agg  = tpath ? aggt : aggs;
    int rows          = tpath ? rows_t : rows_s;

    __shared__ float Wl[128 * 64];
    __shared__ float bl[64], gl[64], bel[64];
    int tid = threadIdx.x;
    {
        const float4* W4 = (const float4*)W;
        float4* Wl4 = (float4*)Wl;
        #pragma unroll
        for (int i = 0; i < 8; ++i) Wl4[tid + i * 256] = W4[tid + i * 256];
        if (tid < 64) { bl[tid] = bias[tid]; gl[tid] = g[tid]; bel[tid] = beta[tid]; }
    }
    __syncthreads();

    int gt2 = lb * 256 + tid;
    int pair = gt2 >> 2;
    int q = gt2 & 3, jc = q * 16;
    int r0i = pair * 2, r1i = r0i + 1;
    if (r0i >= rows) return;
    bool h1 = (r1i < rows);
    const float* xr0 = x + (size_t)r0i * 64;
    const float* ar0 = agg + (size_t)r0i * 64;
    const float* xr1 = h1 ? x + (size_t)r1i * 64 : xr0;
    const float* ar1 = h1 ? agg + (size_t)r1i * 64 : ar0;

    const float4* bj = (const float4*)(bl + jc);
    float4 A0 = bj[0], A1 = bj[1], A2 = bj[2], A3 = bj[3];
    float4 B0 = bj[0], B1 = bj[1], B2 = bj[2], B3 = bj[3];

    #pragma unroll
    for (int kb = 0; kb < 64; kb += 4) {
        float4 i0 = *(const float4*)(xr0 + kb);
        float4 i1 = *(const float4*)(xr1 + kb);
        FMA4R2(i0.x, i1.x, Wl + (kb + 0) * 64 + jc, A0,A1,A2,A3, B0,B1,B2,B3);
        FMA4R2(i0.y, i1.y, Wl + (kb + 1) * 64 + jc, A0,A1,A2,A3, B0,B1,B2,B3);
        FMA4R2(i0.z, i1.z, Wl + (kb + 2) * 64 + jc, A0,A1,A2,A3, B0,B1,B2,B3);
        FMA4R2(i0.w, i1.w, Wl + (kb + 3) * 64 + jc, A0,A1,A2,A3, B0,B1,B2,B3);
    }
    #pragma unroll
    for (int kb = 0; kb < 64; kb += 4) {
        float4 i0 = *(const float4*)(ar0 + kb);
        float4 i1 = *(const float4*)(ar1 + kb);
        FMA4R2(i0.x, i1.x, Wl + (64 + kb + 0) * 64 + jc, A0,A1,A2,A3, B0,B1,B2,B3);
        FMA4R2(i0.y, i1.y, Wl + (64 + kb + 1) * 64 + jc, A0,A1,A2,A3, B0,B1,B2,B3);
        FMA4R2(i0.z, i1.z, Wl + (64 + kb + 2) * 64 + jc, A0,A1,A2,A3, B0,B1,B2,B3);
        FMA4R2(i0.w, i1.w, Wl + (64 + kb + 3) * 64 + jc, A0,A1,A2,A3, B0,B1,B2,B3);
    }

    float ls0 = SUM4(A0) + SUM4(A1) + SUM4(A2) + SUM4(A3);
    float ls1 = SUM4(B0) + SUM4(B1) + SUM4(B2) + SUM4(B3);
    ls0 += __shfl_xor(ls0, 1); ls0 += __shfl_xor(ls0, 2);
    ls1 += __shfl_xor(ls1, 1); ls1 += __shfl_xor(ls1, 2);
    float m0 = ls0 * (1.0f / 64.0f), m1 = ls1 * (1.0f / 64.0f);
    float v0 = 0.f, v1 = 0.f;
    VAR4M(A0, m0, v0); VAR4M(A1, m0, v0); VAR4M(A2, m0, v0); VAR4M(A3, m0, v0);
    VAR4M(B0, m1, v1); VAR4M(B1, m1, v1); VAR4M(B2, m1, v1); VAR4M(B3, m1, v1);
    v0 += __shfl_xor(v0, 1); v0 += __shfl_xor(v0, 2);
    v1 += __shfl_xor(v1, 1); v1 += __shfl_xor(v1, 2);
    float inv0 = rsqrtf(v0 * (1.0f / 64.0f) + 1e-5f);
    float inv1 = rsqrtf(v1 * (1.0f / 64.0f) + 1e-5f);

    const float4* gg4 = (const float4*)(gl + jc);
    const float4* bb4 = (const float4*)(bel + jc);
    #define OUTC(Aj, c, mm, iv, xrp, xwp) do {                                \
        float4 xv = ((const float4*)(xrp))[c];                                \
        float4 gg = gg4[c]; float4 bb = bb4[c];                               \
        float4 y;                                                             \
        y.x = fmaxf((Aj.x - mm) * iv * gg.x + bb.x, 0.f) + xv.x;              \
        y.y = fmaxf((Aj.y - mm) * iv * gg.y + bb.y, 0.f) + xv.y;              \
        y.z = fmaxf((Aj.z - mm) * iv * gg.z + bb.z, 0.f) + xv.z;              \
        y.w = fmaxf((Aj.w - mm) * iv * gg.w + bb.w, 0.f) + xv.w;              \
        ((float4*)(xwp))[c] = y; } while (0)
    float* xw0 = x + (size_t)r0i * 64 + jc;
    OUTC(A0, 0, m0, inv0, xr0 + jc, xw0); OUTC(A1, 1, m0, inv0, xr0 + jc, xw0);
    OUTC(A2, 2, m0, inv0, xr0 + jc, xw0); OUTC(A3, 3, m0, inv0, xr0 + jc, xw0);
    if (h1) {
        float* xw1 = x + (size_t)r1i * 64 + jc;
        OUTC(B0, 0, m1, inv1, xr1 + jc, xw1); OUTC(B1, 1, m1, inv1, xr1 + jc, xw1);
        OUTC(B2, 2, m1, inv1, xr1 + jc, xw1); OUTC(B3, 3, m1, inv1, xr1 + jc, xw1);
    }
    #undef OUTC
}

// ---- fusion: 4 threads/row, single-row (round-7 known-good) ----
__global__ __launch_bounds__(256) void k_fuse(
    const float* __restrict__ W1, const float* __restrict__ b1,
    const float* __restrict__ W2, const float* __restrict__ b2,
    float* __restrict__ out, const float* __restrict__ z, int N, int rows)
{
    __shared__ float W1l[128 * 64];
    __shared__ float W2l[64 * 64];
    __shared__ float b1l[64], b2l[64];
    int tid = threadIdx.x;
    {
        const float4* Wa = (const float4*)W1;
        float4* Wla = (float4*)W1l;
        #pragma unroll
        for (int i = 0; i < 8; ++i) Wla[tid + i * 256] = Wa[tid + i * 256];
        const float4* Wb = (const float4*)W2;
        float4* Wlb = (float4*)W2l;
        #pragma unroll
        for (int i = 0; i < 4; ++i) Wlb[tid + i * 256] = Wb[tid + i * 256];
        if (tid < 64) { b1l[tid] = b1[tid]; b2l[tid] = b2[tid]; }
    }
    __syncthreads();

    int gt2 = blockIdx.x * 256 + tid;
    int row = gt2 >> 2;
    int q = gt2 & 3;
    int jc = q * 16;
    if (row >= rows) return;
    int n = row % N;
    const float* hr = out + (size_t)row * 64;
    const float* zr = z + (size_t)n * 64;
    int lane = tid & 63;

    const float4* bj = (const float4*)(b1l + jc);
    float4 F0 = bj[0], F1 = bj[1], F2 = bj[2], F3 = bj[3];
    #pragma unroll
    for (int kb = 0; kb < 64; kb += 4) {
        float4 iv = *(const float4*)(hr + kb);
        FMA4R(iv.x, W1l + (kb + 0) * 64 + jc, F0, F1, F2, F3);
        FMA4R(iv.y, W1l + (kb + 1) * 64 + jc, F0, F1, F2, F3);
        FMA4R(iv.z, W1l + (kb + 2) * 64 + jc, F0, F1, F2, F3);
        FMA4R(iv.w, W1l + (kb + 3) * 64 + jc, F0, F1, F2, F3);
    }
    #pragma unroll
    for (int kb = 0; kb < 64; kb += 4) {
        float4 iv = *(const float4*)(zr + kb);
        FMA4R(iv.x, W1l + (64 + kb + 0) * 64 + jc, F0, F1, F2, F3);
        FMA4R(iv.y, W1l + (64 + kb + 1) * 64 + jc, F0, F1, F2, F3);
        FMA4R(iv.z, W1l + (64 + kb + 2) * 64 + jc, F0, F1, F2, F3);
        FMA4R(iv.w, W1l + (64 + kb + 3) * 64 + jc, F0, F1, F2, F3);
    }
    F0.x = fmaxf(F0.x, 0.f); F0.y = fmaxf(F0.y, 0.f); F0.z = fmaxf(F0.z, 0.f); F0.w = fmaxf(F0.w, 0.f);
    F1.x = fmaxf(F1.x, 0.f); F1.y = fmaxf(F1.y, 0.f); F1.z = fmaxf(F1.z, 0.f); F1.w = fmaxf(F1.w, 0.f);
    F2.x = fmaxf(F2.x, 0.f); F2.y = fmaxf(F2.y, 0.f); F2.z = fmaxf(F2.z, 0.f); F2.w = fmaxf(F2.w, 0.f);
    F3.x = fmaxf(F3.x, 0.f); F3.y = fmaxf(F3.y, 0.f); F3.z = fmaxf(F3.z, 0.f); F3.w = fmaxf(F3.w, 0.f);

    const float4* bj2 = (const float4*)(b2l + jc);
    float4 O0 = bj2[0], O1 = bj2[1], O2 = bj2[2], O3 = bj2[3];
    int srcLane = (lane & ~3) | ((q + 1) & 3);
    #pragma unroll
    for (int s = 0; s < 4; ++s) {
        int c = (q + s) & 3;
        const float* w2 = W2l + (c * 16) * 64 + jc;
        FMA4R(F0.x, w2 + 0 * 64,  O0, O1, O2, O3);
        FMA4R(F0.y, w2 + 1 * 64,  O0, O1, O2, O3);
        FMA4R(F0.z, w2 + 2 * 64,  O0, O1, O2, O3);
        FMA4R(F0.w, w2 + 3 * 64,  O0, O1, O2, O3);
        FMA4R(F1.x, w2 + 4 * 64,  O0, O1, O2, O3);
        FMA4R(F1.y, w2 + 5 * 64,  O0, O1, O2, O3);
        FMA4R(F1.z, w2 + 6 * 64,  O0, O1, O2, O3);
        FMA4R(F1.w, w2 + 7 * 64,  O0, O1, O2, O3);
        FMA4R(F2.x, w2 + 8 * 64,  O0, O1, O2, O3);
        FMA4R(F2.y, w2 + 9 * 64,  O0, O1, O2, O3);
        FMA4R(F2.z, w2 + 10 * 64, O0, O1, O2, O3);
        FMA4R(F2.w, w2 + 11 * 64, O0, O1, O2, O3);
        FMA4R(F3.x, w2 + 12 * 64, O0, O1, O2, O3);
        FMA4R(F3.y, w2 + 13 * 64, O0, O1, O2, O3);
        FMA4R(F3.z, w2 + 14 * 64, O0, O1, O2, O3);
        FMA4R(F3.w, w2 + 15 * 64, O0, O1, O2, O3);
        if (s < 3) {
            F0.x = __shfl(F0.x, srcLane); F0.y = __shfl(F0.y, srcLane);
            F0.z = __shfl(F0.z, srcLane); F0.w = __shfl(F0.w, srcLane);
            F1.x = __shfl(F1.x, srcLane); F1.y = __shfl(F1.y, srcLane);
            F1.z = __shfl(F1.z, srcLane); F1.w = __shfl(F1.w, srcLane);
            F2.x = __shfl(F2.x, srcLane); F2.y = __shfl(F2.y, srcLane);
            F2.z = __shfl(F2.z, srcLane); F2.w = __shfl(F2.w, srcLane);
            F3.x = __shfl(F3.x, srcLane); F3.y = __shfl(F3.y, srcLane);
            F3.z = __shfl(F3.z, srcLane); F3.w = __shfl(F3.w, srcLane);
        }
    }
    float4* ow4 = (float4*)(out + (size_t)row * 64 + jc);
    ow4[0] = O0; ow4[1] = O1; ow4[2] = O2; ow4[3] = O3;
}

extern "C" void kernel_launch(void* const* d_in, const int* in_sizes, int n_in,
                              void* d_out, int out_size, void* d_ws, size_t ws_size,
                              hipStream_t stream)
{
    const float* rel_text_init = (const float*)d_in[0];
    const float* struct_rel    = (const float*)d_in[1];
    const float* struct_W      = (const float*)d_in[2];
    const float* struct_b      = (const float*)d_in[3];
    const float* struct_g      = (const float*)d_in[4];
    const float* struct_beta   = (const float*)d_in[5];
    const float* text_rel      = (const float*)d_in[6];
    const float* text_W        = (const float*)d_in[7];
    const float* text_b        = (const float*)d_in[8];
    const float* text_g        = (const float*)d_in[9];
    const float* text_beta     = (const float*)d_in[10];
    const float* fuse_W1       = (const float*)d_in[11];
    const float* fuse_b1       = (const float*)d_in[12];
    const float* fuse_W2       = (const float*)d_in[13];
    const float* fuse_b2       = (const float*)d_in[14];
    const int*   h_index       = (const int*)d_in[15];
    const int*   edge_index    = (const int*)d_in[16];
    const int*   edge_type     = (const int*)d_in[17];
    const int*   text_edge_idx = (const int*)d_in[18];

    const int B  = in_sizes[15];
    const int N  = in_sizes[0] / 64;
    const int E  = in_sizes[17];
    const int ET = in_sizes[18] / 2;
    const int L  = in_sizes[3] / 64;
    const int R  = in_sizes[1] / (L * 64);

    const int* src  = edge_index;
    const int* dst  = edge_index + E;
    const int* tsrc = text_edge_idx;
    const int* tdst = text_edge_idx + ET;

    // ---- workspace layout ----
    float* x_t   = (float*)d_ws;                     // [N,64]
    float* agg_t = x_t + (size_t)N * 64;             // [N,64]
    float* agg_s = agg_t + (size_t)N * 64;           // [B,N,64]
    int*   cnt_s = (int*)(agg_s + (size_t)B * N * 64);  // [N]
    int*   off_s = cnt_s + N;                        // [N+1]
    int*   pk_s  = off_s + N + 1;                    // [E]
    int*   cnt_t = pk_s + E;                         // [N]
    int*   off_t = cnt_t + N;                        // [N+1]
    int*   pk_t  = off_t + N + 1;                    // [ET]
    int*   bsum_s = pk_t + ET;                       // [<=1024]
    int*   bsum_t = bsum_s + 1024;                   // [<=1024]

    float* x_s = (float*)d_out;                      // [B,N,64]

    const size_t nd  = (size_t)N * 64;
    const int rows_s = B * N;
    const int tot_s  = rows_s * 64;
    const int nb     = (N + 1023) / 1024;

    const int gb_init   = (tot_s + 255) / 256;
    const int gb_hist   = (E + ET + 255) / 256;
    const int gb_wave_n = (N * 64 + 255) / 256;
    const int pairs_s   = (rows_s + 1) / 2;
    const int pairs_t   = (N + 1) / 2;
    const int bs_blocks = (pairs_s * 4 + 255) / 256;
    const int bt_blocks = (pairs_t * 4 + 255) / 256;
    const int gb_fuse   = (rows_s * 4 + 255) / 256;

    // ---- CSR builds ----
    hipMemsetAsync(cnt_s, 0, (size_t)N * 4, stream);
    hipMemsetAsync(cnt_t, 0, (size_t)N * 4, stream);
    k_hist_all<<<gb_hist, 256, 0, stream>>>(dst, tdst, cnt_s, cnt_t, E, ET);
    k_scan_blk2<<<2 * nb, 1024, 0, stream>>>(cnt_s, off_s, bsum_s,
                                             cnt_t, off_t, bsum_t, N, nb);
    k_scan_top2<<<2, 1024, 0, stream>>>(bsum_s, bsum_t, nb);
    k_scan_add2<<<2 * nb, 1024, 0, stream>>>(bsum_s, off_s, bsum_t, off_t, N, nb);
    k_fill_all<<<gb_hist, 256, 0, stream>>>(src, dst, edge_type, off_s, cnt_s, pk_s,
                                            tsrc, tdst, off_t, cnt_t, pk_t, E, ET);

    // ---- boundaries ----
    k_init_onehot<<<gb_init, 256, 0, stream>>>(x_s, h_index, N, tot_s);
    hipMemcpyAsync(x_t, rel_text_init, nd * sizeof(float),
                   hipMemcpyDeviceToDevice, stream);

    // ---- 6 layers, both branches per launch ----
    for (int i = 0; i < L; ++i) {
        if (B == 2) {
            k_gather_all<<<2 * gb_wave_n, 256, 0, stream>>>(
                x_s, agg_s, off_s, pk_s, struct_rel + (size_t)i * R * 64, h_index,
                x_t, agg_t, off_t, pk_t, text_rel + (size_t)i * 64, rel_text_init,
                N, gb_wave_n, gb_wave_n);
        } else {
            k_gather_struct_gen<<<(rows_s * 64 + 255) / 256, 256, 0, stream>>>(
                x_s, agg_s, off_s, pk_s,
                struct_rel + (size_t)i * R * 64, h_index, N, rows_s);
            k_gather_all<<<gb_wave_n, 256, 0, stream>>>(
                x_s, agg_s, off_s, pk_s, struct_rel + (size_t)i * R * 64, h_index,
                x_t, agg_t, off_t, pk_t, text_rel + (size_t)i * 64, rel_text_init,
                N, 0, gb_wave_n);
        }
        k_update_all<<<bs_blocks + bt_blocks, 256, 0, stream>>>(
            struct_W + (size_t)i * 128 * 64, struct_b + i * 64,
            struct_g + i * 64, struct_beta + i * 64, x_s, agg_s, rows_s,
            text_W + (size_t)i * 128 * 64, text_b + i * 64,
            text_g + i * 64, text_beta + i * 64, x_t, agg_t, N,
            bs_blocks, bt_blocks);
    }

    // ---- fusion ----
    k_fuse<<<gb_fuse, 256, 0, stream>>>(
        fuse_W1, fuse_b1, fuse_W2, fuse_b2, x_s, x_t, N, rows_s);
}

// Round 10
// 693.122 us; speedup vs baseline: 1.3804x; 1.0390x over previous
//
#include <hip/hip_runtime.h>

// ---------------------------------------------------------------------------
// SemmaRelModel: two 6-layer NBFNet branches + MLP fusion.
// Round 10: bf16 mirror of node state for gather's random reads.
//   Round-9 evidence: struct gather is L2-fill bound (FETCH 82MB/dispatch,
//   1.3TB/s effective, VALU 27%) -> halve bytes/edge. fp32 master state,
//   fp32 accumulation, fp32 dense math; only gather operands are bf16.
// ---------------------------------------------------------------------------

__device__ __forceinline__ float bf2f(unsigned short u) {
    return __uint_as_float(((unsigned)u) << 16);
}
__device__ __forceinline__ unsigned short f2bf(float f) {
    unsigned u = __float_as_uint(f);
    u += 0x7FFF + ((u >> 16) & 1);          // round-to-nearest-even
    return (unsigned short)(u >> 16);
}
#define PACK2(a, b) ((unsigned)f2bf(a) | ((unsigned)f2bf(b) << 16))

#define FMA4R(v, wbase, R0, R1, R2, R3) do {                                  \
    const float4* _w = (const float4*)(wbase); float4 _t;                     \
    _t=_w[0]; R0.x=fmaf(v,_t.x,R0.x); R0.y=fmaf(v,_t.y,R0.y); R0.z=fmaf(v,_t.z,R0.z); R0.w=fmaf(v,_t.w,R0.w); \
    _t=_w[1]; R1.x=fmaf(v,_t.x,R1.x); R1.y=fmaf(v,_t.y,R1.y); R1.z=fmaf(v,_t.z,R1.z); R1.w=fmaf(v,_t.w,R1.w); \
    _t=_w[2]; R2.x=fmaf(v,_t.x,R2.x); R2.y=fmaf(v,_t.y,R2.y); R2.z=fmaf(v,_t.z,R2.z); R2.w=fmaf(v,_t.w,R2.w); \
    _t=_w[3]; R3.x=fmaf(v,_t.x,R3.x); R3.y=fmaf(v,_t.y,R3.y); R3.z=fmaf(v,_t.z,R3.z); R3.w=fmaf(v,_t.w,R3.w); \
} while (0)

#define FMA4R2(v0, v1, wbase, P0,P1,P2,P3, Q0,Q1,Q2,Q3) do {                  \
    const float4* _w = (const float4*)(wbase); float4 _t;                     \
    _t=_w[0];                                                                 \
    P0.x=fmaf(v0,_t.x,P0.x); P0.y=fmaf(v0,_t.y,P0.y); P0.z=fmaf(v0,_t.z,P0.z); P0.w=fmaf(v0,_t.w,P0.w); \
    Q0.x=fmaf(v1,_t.x,Q0.x); Q0.y=fmaf(v1,_t.y,Q0.y); Q0.z=fmaf(v1,_t.z,Q0.z); Q0.w=fmaf(v1,_t.w,Q0.w); \
    _t=_w[1];                                                                 \
    P1.x=fmaf(v0,_t.x,P1.x); P1.y=fmaf(v0,_t.y,P1.y); P1.z=fmaf(v0,_t.z,P1.z); P1.w=fmaf(v0,_t.w,P1.w); \
    Q1.x=fmaf(v1,_t.x,Q1.x); Q1.y=fmaf(v1,_t.y,Q1.y); Q1.z=fmaf(v1,_t.z,Q1.z); Q1.w=fmaf(v1,_t.w,Q1.w); \
    _t=_w[2];                                                                 \
    P2.x=fmaf(v0,_t.x,P2.x); P2.y=fmaf(v0,_t.y,P2.y); P2.z=fmaf(v0,_t.z,P2.z); P2.w=fmaf(v0,_t.w,P2.w); \
    Q2.x=fmaf(v1,_t.x,Q2.x); Q2.y=fmaf(v1,_t.y,Q2.y); Q2.z=fmaf(v1,_t.z,Q2.z); Q2.w=fmaf(v1,_t.w,Q2.w); \
    _t=_w[3];                                                                 \
    P3.x=fmaf(v0,_t.x,P3.x); P3.y=fmaf(v0,_t.y,P3.y); P3.z=fmaf(v0,_t.z,P3.z); P3.w=fmaf(v0,_t.w,P3.w); \
    Q3.x=fmaf(v1,_t.x,Q3.x); Q3.y=fmaf(v1,_t.y,Q3.y); Q3.z=fmaf(v1,_t.z,Q3.z); Q3.w=fmaf(v1,_t.w,Q3.w); \
} while (0)

#define SUM4(Ai) ((Ai.x + Ai.y) + (Ai.z + Ai.w))
#define VAR4M(Ai, mm, vv) do { float _c;                                      \
    _c = Ai.x - mm; vv = fmaf(_c, _c, vv); _c = Ai.y - mm; vv = fmaf(_c, _c, vv); \
    _c = Ai.z - mm; vv = fmaf(_c, _c, vv); _c = Ai.w - mm; vv = fmaf(_c, _c, vv); \
} while (0)

#define RSEL(ty) (((ty) < 2) ? ((ty) == 0 ? r0 : r1) : ((ty) == 2 ? r2 : r3))

__global__ __launch_bounds__(256) void k_init_onehot(
    float* __restrict__ x, unsigned short* __restrict__ xbf,
    const int* __restrict__ h_index, int N, int total)
{
    int idx = blockIdx.x * 256 + threadIdx.x;
    if (idx >= total) return;
    int row = idx >> 6;
    int b = row / N;
    int n = row - b * N;
    bool hit = (n == h_index[b]);
    x[idx] = hit ? 1.0f : 0.0f;
    xbf[idx] = hit ? 0x3F80 : 0;
}

__global__ __launch_bounds__(256) void k_cast_init(
    const float* __restrict__ init, float* __restrict__ x,
    unsigned short* __restrict__ xbf, int total)
{
    int idx = blockIdx.x * 256 + threadIdx.x;
    if (idx >= total) return;
    float f = init[idx];
    x[idx] = f;
    xbf[idx] = f2bf(f);
}

// ---- CSR build (both graphs per launch) ----
__global__ __launch_bounds__(256) void k_hist_all(
    const int* __restrict__ dst_s, const int* __restrict__ dst_t,
    int* __restrict__ cnt_s, int* __restrict__ cnt_t, int E, int ET)
{
    int i = blockIdx.x * 256 + threadIdx.x;
    if (i < E) atomicAdd(&cnt_s[dst_s[i]], 1);
    else if (i < E + ET) atomicAdd(&cnt_t[dst_t[i - E]], 1);
}

__global__ __launch_bounds__(1024) void k_scan_blk2(
    const int* __restrict__ cnt_s, int* __restrict__ off_s, int* __restrict__ bsum_s,
    const int* __restrict__ cnt_t, int* __restrict__ off_t, int* __restrict__ bsum_t,
    int n, int nb)
{
    bool tpath = blockIdx.x >= nb;
    int lb = tpath ? blockIdx.x - nb : blockIdx.x;
    const int* cnt = tpath ? cnt_t : cnt_s;
    int* off = tpath ? off_t : off_s;
    int* bsum = tpath ? bsum_t : bsum_s;

    __shared__ int wsum[16], wpre[16], tot;
    int tid = threadIdx.x, lane = tid & 63, w = tid >> 6;
    int i = lb * 1024 + tid;
    int v = (i < n) ? cnt[i] : 0;
    int s = v;
    #pragma unroll
    for (int d = 1; d < 64; d <<= 1) {
        int t = __shfl_up(s, d);
        if (lane >= d) s += t;
    }
    if (lane == 63) wsum[w] = s;
    __syncthreads();
    if (w == 0 && lane < 16) {
        int ws = wsum[lane];
        int p = ws;
        #pragma unroll
        for (int d = 1; d < 16; d <<= 1) {
            int t = __shfl_up(p, d);
            if (lane >= d) p += t;
        }
        wpre[lane] = p - ws;
        if (lane == 15) tot = p;
    }
    __syncthreads();
    if (i < n) off[i + 1] = wpre[w] + s;
    if (tid == 0) {
        bsum[lb] = tot;
        if (lb == 0) off[0] = 0;
    }
}

__global__ __launch_bounds__(1024) void k_scan_top2(
    int* __restrict__ bsum_s, int* __restrict__ bsum_t, int nb)
{
    int* bsum = (blockIdx.x == 0) ? bsum_s : bsum_t;
    __shared__ int wsum[16], wpre[16];
    int tid = threadIdx.x, lane = tid & 63, w = tid >> 6;
    int v = (tid < nb) ? bsum[tid] : 0;
    int s = v;
    #pragma unroll
    for (int d = 1; d < 64; d <<= 1) {
        int t = __shfl_up(s, d);
        if (lane >= d) s += t;
    }
    if (lane == 63) wsum[w] = s;
    __syncthreads();
    if (w == 0 && lane < 16) {
        int ws = wsum[lane];
        int p = ws;
        #pragma unroll
        for (int d = 1; d < 16; d <<= 1) {
            int t = __shfl_up(p, d);
            if (lane >= d) p += t;
        }
        wpre[lane] = p - ws;
    }
    __syncthreads();
    if (tid < nb) bsum[tid] = wpre[w] + s - v;
}

__global__ __launch_bounds__(1024) void k_scan_add2(
    const int* __restrict__ bsum_s, int* __restrict__ off_s,
    const int* __restrict__ bsum_t, int* __restrict__ off_t, int n, int nb)
{
    bool tpath = blockIdx.x >= nb;
    int lb = tpath ? blockIdx.x - nb : blockIdx.x;
    int i = lb * 1024 + threadIdx.x;
    if (i < n) (tpath ? off_t : off_s)[i + 1] += (tpath ? bsum_t : bsum_s)[lb];
}

__global__ __launch_bounds__(256) void k_fill_all(
    const int* __restrict__ src_s, const int* __restrict__ dst_s,
    const int* __restrict__ etype,
    const int* __restrict__ off_s, int* __restrict__ cnt_s, int* __restrict__ pk_s,
    const int* __restrict__ src_t, const int* __restrict__ dst_t,
    const int* __restrict__ off_t, int* __restrict__ cnt_t, int* __restrict__ pk_t,
    int E, int ET)
{
    int i = blockIdx.x * 256 + threadIdx.x;
    if (i < E) {
        int d = dst_s[i];
        int pos = off_s[d] + atomicSub(&cnt_s[d], 1) - 1;
        pk_s[pos] = src_s[i] | (etype[i] << 27);
    } else if (i < E + ET) {
        int e = i - E;
        int d = dst_t[e];
        int pos = off_t[d] + atomicSub(&cnt_t[d], 1) - 1;
        pk_t[pos] = src_t[e];
    }
}

// ---- combined aggregation: struct (both batches) + text; bf16 row reads ----
__global__ __launch_bounds__(256) void k_gather_all(
    const unsigned short* __restrict__ xbs, float* __restrict__ aggs,
    const int* __restrict__ offs, const int* __restrict__ pks,
    const float* __restrict__ rels,      // [4,64]
    const int* __restrict__ hidx,
    const unsigned short* __restrict__ xbt, float* __restrict__ aggt,
    const int* __restrict__ offt, const int* __restrict__ pkt,
    const float* __restrict__ relt,      // [64]
    const float* __restrict__ init,      // [N,64]
    int N, int sblocks, int tblocks)
{
    int tid = threadIdx.x;
    int lane = tid & 63;
    bool isStruct; int lb;
    if (sblocks == tblocks) { isStruct = !(blockIdx.x & 1); lb = blockIdx.x >> 1; }
    else if ((int)blockIdx.x < sblocks) { isStruct = true; lb = blockIdx.x; }
    else { isStruct = false; lb = blockIdx.x - sblocks; }
    int n = (lb * 256 + tid) >> 6;
    if (n >= N) return;

    if (isStruct) {
        float r0 = rels[lane], r1 = rels[64 + lane];
        float r2 = rels[128 + lane], r3 = rels[192 + lane];
        const unsigned short* x0 = xbs;
        const unsigned short* x1 = xbs + (size_t)N * 64;
        float acc0 = (n == hidx[0]) ? 1.0f : 0.0f;
        float acc1 = (n == hidx[1]) ? 1.0f : 0.0f;
        int p0 = __builtin_amdgcn_readfirstlane(offs[n]);
        int p1 = __builtin_amdgcn_readfirstlane(offs[n + 1]);
        for (int p = p0; p < p1; p += 64) {
            int myPk = (p + lane < p1) ? pks[p + lane] : 0;
            int cnt = min(p1 - p, 64);
            int i = 0;
            for (; i + 4 <= cnt; i += 4) {
                int pka = __shfl(myPk, i + 0), pkb = __shfl(myPk, i + 1);
                int pkc = __shfl(myPk, i + 2), pkd = __shfl(myPk, i + 3);
                int sa = pka & 0x03FFFFFF, ta = pka >> 27;
                int sb = pkb & 0x03FFFFFF, tb = pkb >> 27;
                int sc = pkc & 0x03FFFFFF, tc = pkc >> 27;
                int sd = pkd & 0x03FFFFFF, td = pkd >> 27;
                float ra = RSEL(ta), rb = RSEL(tb), rc = RSEL(tc), rd = RSEL(td);
                float a0 = bf2f(x0[(size_t)sa * 64 + lane]), a1 = bf2f(x1[(size_t)sa * 64 + lane]);
                float b0 = bf2f(x0[(size_t)sb * 64 + lane]), b1 = bf2f(x1[(size_t)sb * 64 + lane]);
                float c0 = bf2f(x0[(size_t)sc * 64 + lane]), c1 = bf2f(x1[(size_t)sc * 64 + lane]);
                float d0 = bf2f(x0[(size_t)sd * 64 + lane]), d1 = bf2f(x1[(size_t)sd * 64 + lane]);
                acc0 = fmaf(a0, ra, acc0); acc1 = fmaf(a1, ra, acc1);
                acc0 = fmaf(b0, rb, acc0); acc1 = fmaf(b1, rb, acc1);
                acc0 = fmaf(c0, rc, acc0); acc1 = fmaf(c1, rc, acc1);
                acc0 = fmaf(d0, rd, acc0); acc1 = fmaf(d1, rd, acc1);
            }
            for (; i < cnt; ++i) {
                int pk = __shfl(myPk, i);
                int s = pk & 0x03FFFFFF, ty = pk >> 27;
                float r = RSEL(ty);
                acc0 = fmaf(bf2f(x0[(size_t)s * 64 + lane]), r, acc0);
                acc1 = fmaf(bf2f(x1[(size_t)s * 64 + lane]), r, acc1);
            }
        }
        aggs[(size_t)n * 64 + lane] = acc0;
        aggs[(size_t)(N + n) * 64 + lane] = acc1;
    } else {
        float r = relt[lane];
        float acc = init[(size_t)n * 64 + lane];
        float acc2 = 0.f;
        int p0 = __builtin_amdgcn_readfirstlane(offt[n]);
        int p1 = __builtin_amdgcn_readfirstlane(offt[n + 1]);
        for (int p = p0; p < p1; p += 64) {
            int myPk = (p + lane < p1) ? pkt[p + lane] : 0;
            int cnt = min(p1 - p, 64);
            int i = 0;
            for (; i + 8 <= cnt; i += 8) {
                int s0 = __shfl(myPk, i + 0), s1 = __shfl(myPk, i + 1);
                int s2 = __shfl(myPk, i + 2), s3 = __shfl(myPk, i + 3);
                int s4 = __shfl(myPk, i + 4), s5 = __shfl(myPk, i + 5);
                int s6 = __shfl(myPk, i + 6), s7 = __shfl(myPk, i + 7);
                float a = bf2f(xbt[(size_t)s0 * 64 + lane]), b = bf2f(xbt[(size_t)s1 * 64 + lane]);
                float c = bf2f(xbt[(size_t)s2 * 64 + lane]), d = bf2f(xbt[(size_t)s3 * 64 + lane]);
                float e = bf2f(xbt[(size_t)s4 * 64 + lane]), f = bf2f(xbt[(size_t)s5 * 64 + lane]);
                float g = bf2f(xbt[(size_t)s6 * 64 + lane]), h = bf2f(xbt[(size_t)s7 * 64 + lane]);
                acc = fmaf(a, r, acc);  acc2 = fmaf(b, r, acc2);
                acc = fmaf(c, r, acc);  acc2 = fmaf(d, r, acc2);
                acc = fmaf(e, r, acc);  acc2 = fmaf(f, r, acc2);
                acc = fmaf(g, r, acc);  acc2 = fmaf(h, r, acc2);
            }
            for (; i < cnt; ++i) {
                int s = __shfl(myPk, i);
                acc = fmaf(bf2f(xbt[(size_t)s * 64 + lane]), r, acc);
            }
        }
        aggt[(size_t)n * 64 + lane] = acc + acc2;
    }
}

// generic fallback (B != 2): fp32 reads, correctness path
__global__ __launch_bounds__(256) void k_gather_struct_gen(
    const float* __restrict__ x, float* __restrict__ agg,
    const int* __restrict__ off, const int* __restrict__ packed,
    const float* __restrict__ rel, const int* __restrict__ h_index,
    int N, int BN)
{
    int wid = (blockIdx.x * 256 + threadIdx.x) >> 6;
    int lane = threadIdx.x & 63;
    if (wid >= BN) return;
    int b = wid / N;
    int n = wid - b * N;
    float r0 = rel[lane], r1 = rel[64 + lane];
    float r2 = rel[128 + lane], r3 = rel[192 + lane];
    const float* xb = x + (size_t)b * N * 64;
    float acc = (n == h_index[b]) ? 1.0f : 0.0f;
    int p0 = off[n], p1 = off[n + 1];
    for (int p = p0; p < p1; ++p) {
        int pk = packed[p];
        int s = pk & 0x03FFFFFF, ty = pk >> 27;
        acc = fmaf(xb[(size_t)s * 64 + lane], RSEL(ty), acc);
    }
    agg[(size_t)wid * 64 + lane] = acc;
}

// ---- combined dense update: 4 threads/row, 2-row blocking; writes bf16 mirror
__global__ __launch_bounds__(256) void k_update_all(
    const float* __restrict__ Ws, const float* __restrict__ bs_,
    const float* __restrict__ gs, const float* __restrict__ betas,
    float* __restrict__ xs, unsigned short* __restrict__ xbs,
    const float* __restrict__ aggs, int rows_s,
    const float* __restrict__ Wt, const float* __restrict__ bt_,
    const float* __restrict__ gt_, const float* __restrict__ betat,
    float* __restrict__ xt, unsigned short* __restrict__ xbt,
    const float* __restrict__ aggt, int rows_t,
    int bs_blocks, int bt_blocks)
{
    bool tpath; int lb;
    if (bs_blocks == 2 * bt_blocks) {
        int m3 = blockIdx.x % 3, d3 = blockIdx.x / 3;
        if (m3 != 2) { tpath = false; lb = d3 * 2 + m3; }
        else { tpath = true; lb = d3; }
    } else if ((int)blockIdx.x < bs_blocks) { tpath = false; lb = blockIdx.x; }
    else { tpath = true; lb = blockIdx.x - bs_blocks; }

    const float* W    = tpath ? Wt : Ws;
    const float* bias = tpath ? bt_ : bs_;
    const float* g    = tpath ? gt_ : gs;
    const float* beta = tpath ? betat : betas;
    float* x          = tpath ? xt : xs;
    unsigned short* xb = tpath ? xbt : xbs;
    const float* agg  = tpath ? aggt : aggs;
    int rows          = tpath ? rows_t : rows_s;

    __shared__ float Wl[128 * 64];
    __shared__ float bl[64], gl[64], bel[64];
    int tid = threadIdx.x;
    {
        const float4* W4 = (const float4*)W;
        float4* Wl4 = (float4*)Wl;
        #pragma unroll
        for (int i = 0; i < 8; ++i) Wl4[tid + i * 256] = W4[tid + i * 256];
        if (tid < 64) { bl[tid] = bias[tid]; gl[tid] = g[tid]; bel[tid] = beta[tid]; }
    }
    __syncthreads();

    int gt2 = lb * 256 + tid;
    int pair = gt2 >> 2;
    int q = gt2 & 3, jc = q * 16;
    int r0i = pair * 2, r1i = r0i + 1;
    if (r0i >= rows) return;
    bool h1 = (r1i < rows);
    const float* xr0 = x + (size_t)r0i * 64;
    const float* ar0 = agg + (size_t)r0i * 64;
    const float* xr1 = h1 ? x + (size_t)r1i * 64 : xr0;
    const float* ar1 = h1 ? agg + (size_t)r1i * 64 : ar0;

    const float4* bj = (const float4*)(bl + jc);
    float4 A0 = bj[0], A1 = bj[1], A2 = bj[2], A3 = bj[3];
    float4 B0 = bj[0], B1 = bj[1], B2 = bj[2], B3 = bj[3];

    #pragma unroll
    for (int kb = 0; kb < 64; kb += 4) {
        float4 i0 = *(const float4*)(xr0 + kb);
        float4 i1 = *(const float4*)(xr1 + kb);
        FMA4R2(i0.x, i1.x, Wl + (kb + 0) * 64 + jc, A0,A1,A2,A3, B0,B1,B2,B3);
        FMA4R2(i0.y, i1.y, Wl + (kb + 1) * 64 + jc, A0,A1,A2,A3, B0,B1,B2,B3);
        FMA4R2(i0.z, i1.z, Wl + (kb + 2) * 64 + jc, A0,A1,A2,A3, B0,B1,B2,B3);
        FMA4R2(i0.w, i1.w, Wl + (kb + 3) * 64 + jc, A0,A1,A2,A3, B0,B1,B2,B3);
    }
    #pragma unroll
    for (int kb = 0; kb < 64; kb += 4) {
        float4 i0 = *(const float4*)(ar0 + kb);
        float4 i1 = *(const float4*)(ar1 + kb);
        FMA4R2(i0.x, i1.x, Wl + (64 + kb + 0) * 64 + jc, A0,A1,A2,A3, B0,B1,B2,B3);
        FMA4R2(i0.y, i1.y, Wl + (64 + kb + 1) * 64 + jc, A0,A1,A2,A3, B0,B1,B2,B3);
        FMA4R2(i0.z, i1.z, Wl + (64 + kb + 2) * 64 + jc, A0,A1,A2,A3, B0,B1,B2,B3);
        FMA4R2(i0.w, i1.w, Wl + (64 + kb + 3) * 64 + jc, A0,A1,A2,A3, B0,B1,B2,B3);
    }

    float ls0 = SUM4(A0) + SUM4(A1) + SUM4(A2) + SUM4(A3);
    float ls1 = SUM4(B0) + SUM4(B1) + SUM4(B2) + SUM4(B3);
    ls0 += __shfl_xor(ls0, 1); ls0 += __shfl_xor(ls0, 2);
    ls1 += __shfl_xor(ls1, 1); ls1 += __shfl_xor(ls1, 2);
    float m0 = ls0 * (1.0f / 64.0f), m1 = ls1 * (1.0f / 64.0f);
    float v0 = 0.f, v1 = 0.f;
    VAR4M(A0, m0, v0); VAR4M(A1, m0, v0); VAR4M(A2, m0, v0); VAR4M(A3, m0, v0);
    VAR4M(B0, m1, v1); VAR4M(B1, m1, v1); VAR4M(B2, m1, v1); VAR4M(B3, m1, v1);
    v0 += __shfl_xor(v0, 1); v0 += __shfl_xor(v0, 2);
    v1 += __shfl_xor(v1, 1); v1 += __shfl_xor(v1, 2);
    float inv0 = rsqrtf(v0 * (1.0f / 64.0f) + 1e-5f);
    float inv1 = rsqrtf(v1 * (1.0f / 64.0f) + 1e-5f);

    const float4* gg4 = (const float4*)(gl + jc);
    const float4* bb4 = (const float4*)(bel + jc);
    #define OUTC(Aj, c, mm, iv, xrp, xwp, xbm) do {                           \
        float4 xv = ((const float4*)(xrp))[c];                                \
        float4 gg = gg4[c]; float4 bb = bb4[c];                               \
        float4 y;                                                             \
        y.x = fmaxf((Aj.x - mm) * iv * gg.x + bb.x, 0.f) + xv.x;              \
        y.y = fmaxf((Aj.y - mm) * iv * gg.y + bb.y, 0.f) + xv.y;              \
        y.z = fmaxf((Aj.z - mm) * iv * gg.z + bb.z, 0.f) + xv.z;              \
        y.w = fmaxf((Aj.w - mm) * iv * gg.w + bb.w, 0.f) + xv.w;              \
        ((float4*)(xwp))[c] = y;                                              \
        ((uint2*)(xbm))[c] = make_uint2(PACK2(y.x, y.y), PACK2(y.z, y.w));    \
    } while (0)
    float* xw0 = x + (size_t)r0i * 64 + jc;
    unsigned short* xb0 = xb + (size_t)r0i * 64 + jc;
    OUTC(A0, 0, m0, inv0, xr0 + jc, xw0, xb0); OUTC(A1, 1, m0, inv0, xr0 + jc, xw0, xb0);
    OUTC(A2, 2, m0, inv0, xr0 + jc, xw0, xb0); OUTC(A3, 3, m0, inv0, xr0 + jc, xw0, xb0);
    if (h1) {
        float* xw1 = x + (size_t)r1i * 64 + jc;
        unsigned short* xb1 = xb + (size_t)r1i * 64 + jc;
        OUTC(B0, 0, m1, inv1, xr1 + jc, xw1, xb1); OUTC(B1, 1, m1, inv1, xr1 + jc, xw1, xb1);
        OUTC(B2, 2, m1, inv1, xr1 + jc, xw1, xb1); OUTC(B3, 3, m1, inv1, xr1 + jc, xw1, xb1);
    }
    #undef OUTC
}

// ---- fusion: 4 threads/row, single-row (round-7 known-good) ----
__global__ __launch_bounds__(256) void k_fuse(
    const float* __restrict__ W1, const float* __restrict__ b1,
    const float* __restrict__ W2, const float* __restrict__ b2,
    float* __restrict__ out, const float* __restrict__ z, int N, int rows)
{
    __shared__ float W1l[128 * 64];
    __shared__ float W2l[64 * 64];
    __shared__ float b1l[64], b2l[64];
    int tid = threadIdx.x;
    {
        const float4* Wa = (const float4*)W1;
        float4* Wla = (float4*)W1l;
        #pragma unroll
        for (int i = 0; i < 8; ++i) Wla[tid + i * 256] = Wa[tid + i * 256];
        const float4* Wb = (const float4*)W2;
        float4* Wlb = (float4*)W2l;
        #pragma unroll
        for (int i = 0; i < 4; ++i) Wlb[tid + i * 256] = Wb[tid + i * 256];
        if (tid < 64) { b1l[tid] = b1[tid]; b2l[tid] = b2[tid]; }
    }
    __syncthreads();

    int gt2 = blockIdx.x * 256 + tid;
    int row = gt2 >> 2;
    int q = gt2 & 3;
    int jc = q * 16;
    if (row >= rows) return;
    int n = row % N;
    const float* hr = out + (size_t)row * 64;
    const float* zr = z + (size_t)n * 64;
    int lane = tid & 63;

    const float4* bj = (const float4*)(b1l + jc);
    float4 F0 = bj[0], F1 = bj[1], F2 = bj[2], F3 = bj[3];
    #pragma unroll
    for (int kb = 0; kb < 64; kb += 4) {
        float4 iv = *(const float4*)(hr + kb);
        FMA4R(iv.x, W1l + (kb + 0) * 64 + jc, F0, F1, F2, F3);
        FMA4R(iv.y, W1l + (kb + 1) * 64 + jc, F0, F1, F2, F3);
        FMA4R(iv.z, W1l + (kb + 2) * 64 + jc, F0, F1, F2, F3);
        FMA4R(iv.w, W1l + (kb + 3) * 64 + jc, F0, F1, F2, F3);
    }
    #pragma unroll
    for (int kb = 0; kb < 64; kb += 4) {
        float4 iv = *(const float4*)(zr + kb);
        FMA4R(iv.x, W1l + (64 + kb + 0) * 64 + jc, F0, F1, F2, F3);
        FMA4R(iv.y, W1l + (64 + kb + 1) * 64 + jc, F0, F1, F2, F3);
        FMA4R(iv.z, W1l + (64 + kb + 2) * 64 + jc, F0, F1, F2, F3);
        FMA4R(iv.w, W1l + (64 + kb + 3) * 64 + jc, F0, F1, F2, F3);
    }
    F0.x = fmaxf(F0.x, 0.f); F0.y = fmaxf(F0.y, 0.f); F0.z = fmaxf(F0.z, 0.f); F0.w = fmaxf(F0.w, 0.f);
    F1.x = fmaxf(F1.x, 0.f); F1.y = fmaxf(F1.y, 0.f); F1.z = fmaxf(F1.z, 0.f); F1.w = fmaxf(F1.w, 0.f);
    F2.x = fmaxf(F2.x, 0.f); F2.y = fmaxf(F2.y, 0.f); F2.z = fmaxf(F2.z, 0.f); F2.w = fmaxf(F2.w, 0.f);
    F3.x = fmaxf(F3.x, 0.f); F3.y = fmaxf(F3.y, 0.f); F3.z = fmaxf(F3.z, 0.f); F3.w = fmaxf(F3.w, 0.f);

    const float4* bj2 = (const float4*)(b2l + jc);
    float4 O0 = bj2[0], O1 = bj2[1], O2 = bj2[2], O3 = bj2[3];
    int srcLane = (lane & ~3) | ((q + 1) & 3);
    #pragma unroll
    for (int s = 0; s < 4; ++s) {
        int c = (q + s) & 3;
        const float* w2 = W2l + (c * 16) * 64 + jc;
        FMA4R(F0.x, w2 + 0 * 64,  O0, O1, O2, O3);
        FMA4R(F0.y, w2 + 1 * 64,  O0, O1, O2, O3);
        FMA4R(F0.z, w2 + 2 * 64,  O0, O1, O2, O3);
        FMA4R(F0.w, w2 + 3 * 64,  O0, O1, O2, O3);
        FMA4R(F1.x, w2 + 4 * 64,  O0, O1, O2, O3);
        FMA4R(F1.y, w2 + 5 * 64,  O0, O1, O2, O3);
        FMA4R(F1.z, w2 + 6 * 64,  O0, O1, O2, O3);
        FMA4R(F1.w, w2 + 7 * 64,  O0, O1, O2, O3);
        FMA4R(F2.x, w2 + 8 * 64,  O0, O1, O2, O3);
        FMA4R(F2.y, w2 + 9 * 64,  O0, O1, O2, O3);
        FMA4R(F2.z, w2 + 10 * 64, O0, O1, O2, O3);
        FMA4R(F2.w, w2 + 11 * 64, O0, O1, O2, O3);
        FMA4R(F3.x, w2 + 12 * 64, O0, O1, O2, O3);
        FMA4R(F3.y, w2 + 13 * 64, O0, O1, O2, O3);
        FMA4R(F3.z, w2 + 14 * 64, O0, O1, O2, O3);
        FMA4R(F3.w, w2 + 15 * 64, O0, O1, O2, O3);
        if (s < 3) {
            F0.x = __shfl(F0.x, srcLane); F0.y = __shfl(F0.y, srcLane);
            F0.z = __shfl(F0.z, srcLane); F0.w = __shfl(F0.w, srcLane);
            F1.x = __shfl(F1.x, srcLane); F1.y = __shfl(F1.y, srcLane);
            F1.z = __shfl(F1.z, srcLane); F1.w = __shfl(F1.w, srcLane);
            F2.x = __shfl(F2.x, srcLane); F2.y = __shfl(F2.y, srcLane);
            F2.z = __shfl(F2.z, srcLane); F2.w = __shfl(F2.w, srcLane);
            F3.x = __shfl(F3.x, srcLane); F3.y = __shfl(F3.y, srcLane);
            F3.z = __shfl(F3.z, srcLane); F3.w = __shfl(F3.w, srcLane);
        }
    }
    float4* ow4 = (float4*)(out + (size_t)row * 64 + jc);
    ow4[0] = O0; ow4[1] = O1; ow4[2] = O2; ow4[3] = O3;
}

extern "C" void kernel_launch(void* const* d_in, const int* in_sizes, int n_in,
                              void* d_out, int out_size, void* d_ws, size_t ws_size,
                              hipStream_t stream)
{
    const float* rel_text_init = (const float*)d_in[0];
    const float* struct_rel    = (const float*)d_in[1];
    const float* struct_W      = (const float*)d_in[2];
    const float* struct_b      = (const float*)d_in[3];
    const float* struct_g      = (const float*)d_in[4];
    const float* struct_beta   = (const float*)d_in[5];
    const float* text_rel      = (const float*)d_in[6];
    const float* text_W        = (const float*)d_in[7];
    const float* text_b        = (const float*)d_in[8];
    const float* text_g        = (const float*)d_in[9];
    const float* text_beta     = (const float*)d_in[10];
    const float* fuse_W1       = (const float*)d_in[11];
    const float* fuse_b1       = (const float*)d_in[12];
    const float* fuse_W2       = (const float*)d_in[13];
    const float* fuse_b2       = (const float*)d_in[14];
    const int*   h_index       = (const int*)d_in[15];
    const int*   edge_index    = (const int*)d_in[16];
    const int*   edge_type     = (const int*)d_in[17];
    const int*   text_edge_idx = (const int*)d_in[18];

    const int B  = in_sizes[15];
    const int N  = in_sizes[0] / 64;
    const int E  = in_sizes[17];
    const int ET = in_sizes[18] / 2;
    const int L  = in_sizes[3] / 64;
    const int R  = in_sizes[1] / (L * 64);

    const int* src  = edge_index;
    const int* dst  = edge_index + E;
    const int* tsrc = text_edge_idx;
    const int* tdst = text_edge_idx + ET;

    // ---- workspace layout ----
    float* x_t   = (float*)d_ws;                        // [N,64]
    float* agg_t = x_t + (size_t)N * 64;                // [N,64]
    float* agg_s = agg_t + (size_t)N * 64;              // [B,N,64]
    unsigned short* xbf_s = (unsigned short*)(agg_s + (size_t)B * N * 64); // [B*N,64]
    unsigned short* xbf_t = xbf_s + (size_t)B * N * 64; // [N,64]
    int*   cnt_s = (int*)(xbf_t + (size_t)N * 64);      // [N]
    int*   off_s = cnt_s + N;                           // [N+1]
    int*   pk_s  = off_s + N + 1;                       // [E]
    int*   cnt_t = pk_s + E;                            // [N]
    int*   off_t = cnt_t + N;                           // [N+1]
    int*   pk_t  = off_t + N + 1;                       // [ET]
    int*   bsum_s = pk_t + ET;                          // [<=1024]
    int*   bsum_t = bsum_s + 1024;                      // [<=1024]

    float* x_s = (float*)d_out;                         // [B,N,64]

    const size_t nd  = (size_t)N * 64;
    const int rows_s = B * N;
    const int tot_s  = rows_s * 64;
    const int nb     = (N + 1023) / 1024;

    const int gb_init   = (tot_s + 255) / 256;
    const int gb_castt  = ((int)nd + 255) / 256;
    const int gb_hist   = (E + ET + 255) / 256;
    const int gb_wave_n = (N * 64 + 255) / 256;
    const int pairs_s   = (rows_s + 1) / 2;
    const int pairs_t   = (N + 1) / 2;
    const int bs_blocks = (pairs_s * 4 + 255) / 256;
    const int bt_blocks = (pairs_t * 4 + 255) / 256;
    const int gb_fuse   = (rows_s * 4 + 255) / 256;

    // ---- CSR builds ----
    hipMemsetAsync(cnt_s, 0, (size_t)N * 4, stream);
    hipMemsetAsync(cnt_t, 0, (size_t)N * 4, stream);
    k_hist_all<<<gb_hist, 256, 0, stream>>>(dst, tdst, cnt_s, cnt_t, E, ET);
    k_scan_blk2<<<2 * nb, 1024, 0, stream>>>(cnt_s, off_s, bsum_s,
                                             cnt_t, off_t, bsum_t, N, nb);
    k_scan_top2<<<2, 1024, 0, stream>>>(bsum_s, bsum_t, nb);
    k_scan_add2<<<2 * nb, 1024, 0, stream>>>(bsum_s, off_s, bsum_t, off_t, N, nb);
    k_fill_all<<<gb_hist, 256, 0, stream>>>(src, dst, edge_type, off_s, cnt_s, pk_s,
                                            tsrc, tdst, off_t, cnt_t, pk_t, E, ET);

    // ---- boundaries ----
    k_init_onehot<<<gb_init, 256, 0, stream>>>(x_s, xbf_s, h_index, N, tot_s);
    k_cast_init<<<gb_castt, 256, 0, stream>>>(rel_text_init, x_t, xbf_t, (int)nd);

    // ---- 6 layers, both branches per launch ----
    for (int i = 0; i < L; ++i) {
        if (B == 2) {
            k_gather_all<<<2 * gb_wave_n, 256, 0, stream>>>(
                xbf_s, agg_s, off_s, pk_s, struct_rel + (size_t)i * R * 64, h_index,
                xbf_t, agg_t, off_t, pk_t, text_rel + (size_t)i * 64, rel_text_init,
                N, gb_wave_n, gb_wave_n);
        } else {
            k_gather_struct_gen<<<(rows_s * 64 + 255) / 256, 256, 0, stream>>>(
                x_s, agg_s, off_s, pk_s,
                struct_rel + (size_t)i * R * 64, h_index, N, rows_s);
            k_gather_all<<<gb_wave_n, 256, 0, stream>>>(
                xbf_s, agg_s, off_s, pk_s, struct_rel + (size_t)i * R * 64, h_index,
                xbf_t, agg_t, off_t, pk_t, text_rel + (size_t)i * 64, rel_text_init,
                N, 0, gb_wave_n);
        }
        k_update_all<<<bs_blocks + bt_blocks, 256, 0, stream>>>(
            struct_W + (size_t)i * 128 * 64, struct_b + i * 64,
            struct_g + i * 64, struct_beta + i * 64, x_s, xbf_s, agg_s, rows_s,
            text_W + (size_t)i * 128 * 64, text_b + i * 64,
            text_g + i * 64, text_beta + i * 64, x_t, xbf_t, agg_t, N,
            bs_blocks, bt_blocks);
    }

    // ---- fusion ----
    k_fuse<<<gb_fuse, 256, 0, stream>>>(
        fuse_W1, fuse_b1, fuse_W2, fuse_b2, x_s, x_t, N, rows_s);
}